// Round 6
// baseline (426.699 us; speedup 1.0000x reference)
//
#include <hip/hip_runtime.h>
#include <hip/hip_cooperative_groups.h>
#include <math.h>

namespace cg = cooperative_groups;

#define LQ 1024
#define DD 512
#define DK 64
#define RR 2
#define NBLK 512

typedef unsigned short ushort_t;
typedef __attribute__((ext_vector_type(8))) short bf16x8;
typedef __attribute__((ext_vector_type(4))) float f32x4;

__device__ inline ushort_t bfh(float x) {
    union { float f; unsigned int u; } c; c.f = x;
    unsigned int u = c.u;
    unsigned int r = u + 0x7fffu + ((u >> 16) & 1u);
    return (ushort_t)(r >> 16);
}
__device__ inline float bf2f(ushort_t h) {
    union { unsigned int u; float f; } c; c.u = ((unsigned int)h) << 16;
    return c.f;
}
__device__ inline void store8u(ushort_t* p, const ushort_t h[8]) {
    uint4 v;
    v.x = h[0] | ((unsigned int)h[1] << 16); v.y = h[2] | ((unsigned int)h[3] << 16);
    v.z = h[4] | ((unsigned int)h[5] << 16); v.w = h[6] | ((unsigned int)h[7] << 16);
    *(uint4*)p = v;
}
__device__ inline void store4u(ushort_t* p, const ushort_t h[4]) {
    uint2 v;
    v.x = h[0] | ((unsigned int)h[1] << 16); v.y = h[2] | ((unsigned int)h[3] << 16);
    *(uint2*)p = v;
}

// ================= phase logic (shared by mega + fallback kernels) =================

// ---- P0: prep — bf16 splits + weight transposes. units [0,512) split, [512,1280) transpose ----
__device__ void prep_logic(int u, char* SM,
                           const float* query, const float* value,
                           const float* Wq, const float* Wv, const float* Wo,
                           ushort_t* Qh, ushort_t* Qm, ushort_t* Ql, ushort_t* Vh,
                           ushort_t* WqTh, ushort_t* WqTm, ushort_t* WqTl,
                           ushort_t* WvTh, ushort_t* WoTh) {
    const int tid = threadIdx.x;
    if (u < 512) {
        const bool isq = (u < 256);
        const float* src = isq ? query : value;
        const int base = (isq ? u : u - 256) * 2048 + tid * 8;
        float x[8];
        *(float4*)&x[0] = *(const float4*)(src + base);
        *(float4*)&x[4] = *(const float4*)(src + base + 4);
        ushort_t h[8], m[8], l[8];
#pragma unroll
        for (int i = 0; i < 8; ++i) {
            h[i] = bfh(x[i]);
            float r1 = x[i] - bf2f(h[i]);
            m[i] = bfh(r1);
            l[i] = bfh(r1 - bf2f(m[i]));
        }
        if (isq) { store8u(Qh + base, h); store8u(Qm + base, m); store8u(Ql + base, l); }
        else     { store8u(Vh + base, h); }
    } else {
        float (*tl)[33] = (float(*)[33])SM;
        __syncthreads();                       // protect tl reuse across loop iterations
        const int t = u - 512;
        const int mat = t >> 8;                // 0 Wq, 1 Wv, 2 Wo
        const int tile = t & 255;
        const int r0 = (tile >> 4) * 32;
        const int c0 = (tile & 15) * 32;
        const float* W = (mat == 0) ? Wq : ((mat == 1) ? Wv : Wo);
        const int rr = tid >> 3, cc = (tid & 7) * 4;
        *(float4*)&tl[rr][cc] = *(const float4*)(W + (size_t)(r0 + rr) * DD + c0 + cc);
        __syncthreads();
        float y[4];
#pragma unroll
        for (int i = 0; i < 4; ++i) y[i] = tl[cc + i][rr];
        size_t ob = (size_t)(c0 + rr) * DD + r0 + cc;
        if (mat == 0) {
            ushort_t h[4], m[4], l[4];
#pragma unroll
            for (int i = 0; i < 4; ++i) {
                h[i] = bfh(y[i]);
                float r1 = y[i] - bf2f(h[i]);
                m[i] = bfh(r1);
                l[i] = bfh(r1 - bf2f(m[i]));
            }
            store4u(WqTh + ob, h); store4u(WqTm + ob, m); store4u(WqTl + ob, l);
        } else {
            ushort_t h[4];
#pragma unroll
            for (int i = 0; i < 4; ++i) h[i] = bfh(y[i]);
            store4u((mat == 1 ? WvTh : WoTh) + ob, h);
        }
    }
}

// ---- MFMA GEMM core (64x64 tile, 4 waves, 16x16x32 bf16) ----
template <int NLEV>
__device__ void gemm_core(const ushort_t* A0, const ushort_t* A1, const ushort_t* A2,
                          const ushort_t* B0, const ushort_t* B1, const ushort_t* B2,
                          const float* bias, float* out,
                          int m0, int n0, int n_mult, int l_stride, char* lds) {
    const int tid = threadIdx.x;
    const int wave = tid >> 6, lane = tid & 63;
    const int wm = wave >> 1, wn = wave & 1;
    const ushort_t* As[3] = {A0, A1, A2};
    const ushort_t* Bs[3] = {B0, B1, B2};
    f32x4 acc[2][2] = {};
    const int srow = tid >> 2, skb = tid & 3;
    const int sswz = skb ^ ((srow >> 1) & 3);
    const int lofs = srow * 64 + sswz * 16;
    const size_t gbaseA = (size_t)(m0 + srow) * DD + skb * 8;
    const size_t gbaseB = (size_t)(n0 + srow) * DD + skb * 8;
    const int kbr = lane >> 4;
    int aoff[2], boff[2];
#pragma unroll
    for (int f = 0; f < 2; ++f) {
        int ra = wm * 32 + f * 16 + (lane & 15);
        int rb = wn * 32 + f * 16 + (lane & 15);
        aoff[f] = ra * 64 + ((kbr ^ ((ra >> 1) & 3)) << 4);
        boff[f] = rb * 64 + ((kbr ^ ((rb >> 1) & 3)) << 4);
    }
    for (int kt = 0; kt < DD; kt += 32) {
        __syncthreads();
#pragma unroll
        for (int lev = 0; lev < NLEV; ++lev) {
            *(uint4*)(lds + lev * 4096 + lofs) = *(const uint4*)(As[lev] + gbaseA + kt);
            *(uint4*)(lds + (NLEV + lev) * 4096 + lofs) = *(const uint4*)(Bs[lev] + gbaseB + kt);
        }
        __syncthreads();
        bf16x8 af[2][NLEV], bfr[2][NLEV];
#pragma unroll
        for (int f = 0; f < 2; ++f)
#pragma unroll
            for (int lev = 0; lev < NLEV; ++lev) {
                af[f][lev] = *(const bf16x8*)(lds + lev * 4096 + aoff[f]);
                bfr[f][lev] = *(const bf16x8*)(lds + (NLEV + lev) * 4096 + boff[f]);
            }
#pragma unroll
        for (int i = 0; i < 2; ++i)
#pragma unroll
            for (int j = 0; j < 2; ++j)
#pragma unroll
                for (int la = 0; la < NLEV; ++la)
#pragma unroll
                    for (int lb = 0; lb < NLEV; ++lb)
                        if (la + lb <= NLEV - 1)
                            acc[i][j] = __builtin_amdgcn_mfma_f32_16x16x32_bf16(
                                af[i][la], bfr[j][lb], acc[i][j], 0, 0, 0);
    }
#pragma unroll
    for (int i = 0; i < 2; ++i)
#pragma unroll
        for (int j = 0; j < 2; ++j) {
            int cl = wn * 32 + j * 16 + (lane & 15);
            float bb = bias[n0 + cl];
#pragma unroll
            for (int reg = 0; reg < 4; ++reg) {
                int rl = wm * 32 + i * 16 + (lane >> 4) * 4 + reg;
                out[(size_t)n0 * n_mult + (size_t)(m0 + rl) * l_stride + cl] = acc[i][j][reg] + bb;
            }
        }
}

// ---- P2: hash — projections + argmax + row rnorm; nit*4 rows per block ----
__device__ void hash_logic(int blk, int nit, char* SM,
                           const float* Q, const float* rnd, int* HASH, float* RNORM) {
    float (*rmn)[64] = (float(*)[64])SM;
    const int tid = threadIdx.x;
    for (int idx = tid; idx < 4096; idx += 256)
        rmn[idx >> 6][idx & 63] = rnd[idx];
    __syncthreads();
    if (tid < 128) {
        int d = tid >> 1, rh = tid & 1;
        float s = 0.f;
        for (int j = 0; j < 32; ++j) { float x = rmn[d][rh * 32 + j]; s += x * x; }
        float nrm = sqrtf(s);
        for (int j = 0; j < 32; ++j) rmn[d][rh * 32 + j] = rmn[d][rh * 32 + j] / nrm;
    }
    __syncthreads();
    const int w = tid >> 6, lane = tid & 63;
    const int j = lane & 31, r = lane >> 5;
    const int rowbase = blk * nit * 4;
    for (int it = 0; it < nit; ++it) {
        const int row = rowbase + it * 4 + w;
        const int bh = row >> 10, l = row & (LQ - 1);
        float x = Q[(size_t)row * DK + lane];
        float s2 = x * x;
#pragma unroll
        for (int m = 1; m < 64; m <<= 1) s2 += __shfl_xor(s2, m);
        if (lane == 0) RNORM[row] = 1.0f / sqrtf(s2);
        float p0 = 0.f, p1 = 0.f, p2 = 0.f, p3 = 0.f;
#pragma unroll 4
        for (int d = 0; d < 64; d += 4) {
            p0 += __shfl(x, d + 0) * rmn[d + 0][lane];
            p1 += __shfl(x, d + 1) * rmn[d + 1][lane];
            p2 += __shfl(x, d + 2) * rmn[d + 2][lane];
            p3 += __shfl(x, d + 3) * rmn[d + 3][lane];
        }
        float p = (p0 + p1) + (p2 + p3);
        float bv; int bi;
        if (p >= -p) { bv = p; bi = j; } else { bv = -p; bi = 32 + j; }
#pragma unroll
        for (int m = 1; m < 32; m <<= 1) {
            float ov = __shfl_xor(bv, m);
            int oi = __shfl_xor(bi, m);
            if (ov > bv || (ov == bv && oi < bi)) { bv = ov; bi = oi; }
        }
        if (j == 0) HASH[((size_t)bh * RR + r) * LQ + l] = bi;
    }
}

// ---- P3: stable counting sort per pair (u16 counters, shfl base-scan) ----
__device__ void sort_logic(int pair, char* SM, const int* HASH,
                           int* HIDX, int* OIDX, int* HSORT) {
    int* hl = (int*)SM;                                    // 4096 B
    ushort_t (*cnt)[64] = (ushort_t(*)[64])(SM + 4096);    // 32768 B
    int (*psum)[4] = (int(*)[4])(SM + 36864);              // 1024 B
    int (*poff)[4] = (int(*)[4])(SM + 37888);              // 1024 B
    int* base = (int*)(SM + 38912);                        // 256 B
    const int tid = threadIdx.x;
    const int* hsrc = HASH + (size_t)pair * LQ;
    for (int i = tid; i < 1024; i += 256) hl[i] = hsrc[i];
    int* cz = (int*)(SM + 4096);
    for (int i = tid; i < 8192; i += 256) cz[i] = 0;
    __syncthreads();
    for (int i = 0; i < 4; ++i) {
        int h = hl[tid * 4 + i];
        cnt[tid][h] += 1;
    }
    __syncthreads();
    {   // per-bucket segmented exclusive scan over thread index
        int h = tid >> 2, seg = tid & 3;
        int run = 0;
        for (int tt = seg * 64; tt < seg * 64 + 64; ++tt) {
            int tmp = cnt[tt][h];
            cnt[tt][h] = (ushort_t)run;
            run += tmp;
        }
        psum[h][seg] = run;
    }
    __syncthreads();
    if (tid < 64) {
        int run = 0;
#pragma unroll
        for (int seg = 0; seg < 4; ++seg) { int t = psum[tid][seg]; poff[tid][seg] = run; run += t; }
        int incl = run;
#pragma unroll
        for (int d = 1; d < 64; d <<= 1) {
            int y = __shfl_up(incl, d);
            if (tid >= d) incl += y;
        }
        base[tid] = incl - run;
    }
    __syncthreads();
    int* HI = HIDX + (size_t)pair * LQ;
    int* OI = OIDX + (size_t)pair * LQ;
    int* HS = HSORT + (size_t)pair * LQ;
    const int myseg = tid >> 6;
    for (int i = 0; i < 4; ++i) {
        int l = tid * 4 + i;
        int h = hl[l];
        int pos = base[h] + poff[h][myseg] + cnt[tid][h];
        cnt[tid][h] = (ushort_t)(cnt[tid][h] + 1);
        HI[pos] = l;
        OI[l] = pos;
        HS[pos] = h;
    }
}

// ---- P4: fused scores + per-pair softmax partials + PV ----
__device__ void spv_logic(int n, int r, int bh, char* SM,
                          const float* Q, const float* RNORM, const float* Vf,
                          const int* HIDX, const int* OIDX, const int* HSORT,
                          float* PV, float2* ML) {
    const int pair = bh * RR + r;
    float (*Qs)[65] = (float(*)[65])SM;
    float (*Ks)[65] = (float(*)[65])(SM + 8320);
    float (*Vt)[68] = (float(*)[68])SM;                    // overlays Qs/Ks after scores
    float (*Pl)[68] = (float(*)[68])(SM + 25024);
    float (*redm)[8] = (float(*)[8])(SM + 33728);
    float (*redl)[8] = (float(*)[8])(SM + 34752);
    int* qi_l = (int*)(SM + 35776);
    int* hsq  = (int*)(SM + 35904);
    int* Aq   = (int*)(SM + 36032);
    int* ki_l = (int*)(SM + 36160);
    int* hsk  = (int*)(SM + 36416);
    int* Ak   = (int*)(SM + 36672);
    float* krn  = (float*)(SM + 36928);
    float* lcnt = (float*)(SM + 37184);
    const int tid = threadIdx.x;
    const int* HI = HIDX + (size_t)pair * LQ;
    const int* OI = OIDX + (size_t)pair * LQ;
    const int* HS = HSORT + (size_t)pair * LQ;
    if (tid < 32) {
        int s = n * 32 + tid;
        qi_l[tid] = HI[s]; hsq[tid] = HS[s]; Aq[tid] = OI[s];
    } else if (tid < 96) {
        int k = tid - 32;
        int t = (n - 1) * 32 + k;
        if (t < 0) { ki_l[k] = -1; hsk[k] = 0; Ak[k] = 0; krn[k] = 0.f; }
        else {
            int ki = HI[t];
            ki_l[k] = ki; hsk[k] = HS[t]; Ak[k] = OI[t];
            krn[k] = RNORM[(size_t)bh * LQ + ki];
        }
    }
    __syncthreads();
    if (tid == 0) {
        if (n > 0) {
            for (int k = 0; k < 64; ++k) lcnt[k] = 0.f;
        } else {
            int zc = 0;
            for (int k = 32; k < 64; ++k) zc += (Ak[k] == 0);
            float l32 = logf((float)(32 + zc));
            for (int k = 0; k < 32; ++k) lcnt[k] = l32;
            for (int k = 32; k < 64; ++k) lcnt[k] = (Ak[k] == 0) ? l32 : 0.f;
        }
    }
    for (int idx = tid; idx < 32 * 16; idx += 256) {
        int row = idx >> 4, c4 = idx & 15;
        float4 v = ((const float4*)(Q + ((size_t)bh * LQ + qi_l[row]) * DK))[c4];
        Qs[row][c4 * 4 + 0] = v.x; Qs[row][c4 * 4 + 1] = v.y;
        Qs[row][c4 * 4 + 2] = v.z; Qs[row][c4 * 4 + 3] = v.w;
    }
    for (int idx = tid; idx < 64 * 16; idx += 256) {
        int row = idx >> 4, c4 = idx & 15;
        int ki = ki_l[row];
        float4 v;
        if (ki < 0) { v.x = 0.f; v.y = 0.f; v.z = 0.f; v.w = 0.f; }
        else {
            v = ((const float4*)(Q + ((size_t)bh * LQ + ki) * DK))[c4];
            float rn = krn[row];
            v.x *= rn; v.y *= rn; v.z *= rn; v.w *= rn;
        }
        Ks[row][c4 * 4 + 0] = v.x; Ks[row][c4 * 4 + 1] = v.y;
        Ks[row][c4 * 4 + 2] = v.z; Ks[row][c4 * 4 + 3] = v.w;
    }
    __syncthreads();
    const int qq = tid & 31;
    const int g = tid >> 5;
    const int k0 = g * 8;
    float acc[8] = {};
    for (int d = 0; d < 64; ++d) {
        float qv = Qs[qq][d];
#pragma unroll
        for (int kk = 0; kk < 8; ++kk) acc[kk] += qv * Ks[k0 + kk][d];
    }
    const int s = n * 32 + qq;
    const int aq = Aq[qq], hq = hsq[qq];
    float sc[8];
    float pm = -3.4e38f;
#pragma unroll
    for (int kk = 0; kk < 8; ++kk) {
        int k = k0 + kk;
        float v = acc[kk] * 0.125f;                       // / sqrt(dk)
        v = v - ((n == 0 && k < 32) ? 1e9f : 0.f);        // lm (pad mask)
        v = v - ((hq == hsk[k]) ? 0.f : 1e9f);            // heq
        v = v - ((aq > Ak[k]) ? 0.f : 1e9f);              // causal
        v = v - ((aq == Ak[k]) ? 1e5f : 0.f);             // ieq
        v = v - lcnt[k];                                  // log(count)
        sc[kk] = v;
        pm = fmaxf(pm, v);
    }
    redm[qq][g] = pm;
    __syncthreads();                                      // Qs/Ks now dead
    for (int idx = tid; idx < 64 * 16; idx += 256) {
        int row = idx >> 4, c4 = idx & 15;
        int ki = ki_l[row];
        float4 v;
        if (ki < 0) { v.x = 0.f; v.y = 0.f; v.z = 0.f; v.w = 0.f; }
        else v = ((const float4*)(Vf + ((size_t)bh * LQ + ki) * DK))[c4];
        Vt[c4 * 4 + 0][row] = v.x; Vt[c4 * 4 + 1][row] = v.y;
        Vt[c4 * 4 + 2][row] = v.z; Vt[c4 * 4 + 3][row] = v.w;
    }
    float m = redm[qq][0];
#pragma unroll
    for (int t = 1; t < 8; ++t) m = fmaxf(m, redm[qq][t]);
    float psum = 0.f;
#pragma unroll
    for (int kk = 0; kk < 8; ++kk) {
        float e = expf(sc[kk] - m);
        Pl[qq][k0 + kk] = e;
        psum += e;
    }
    redl[qq][g] = psum;
    __syncthreads();
    float lsum = redl[qq][0];
#pragma unroll
    for (int t = 1; t < 8; ++t) lsum += redl[qq][t];
    float o[8] = {};
    for (int k4 = 0; k4 < 16; ++k4) {
        float4 p4 = *(const float4*)&Pl[qq][k4 * 4];
        float pv[4] = {p4.x, p4.y, p4.z, p4.w};
#pragma unroll
        for (int dd = 0; dd < 8; ++dd) {
            float4 v4 = *(const float4*)&Vt[k0 + dd][k4 * 4];
            o[dd] += pv[0] * v4.x + pv[1] * v4.y + pv[2] * v4.z + pv[3] * v4.w;
        }
    }
    float* dst = PV + (((size_t)pair * LQ + s) << 6) + k0;
    float4 o0, o1;
    o0.x = o[0]; o0.y = o[1]; o0.z = o[2]; o0.w = o[3];
    o1.x = o[4]; o1.y = o[5]; o1.z = o[6]; o1.w = o[7];
    *(float4*)dst = o0; *(float4*)(dst + 4) = o1;
    if (g == 0) ML[(size_t)pair * LQ + s] = make_float2(m, lsum);
}

// ---- P5: combine two rounds per row -> ATT bf16 ----
__device__ void combine_logic(int row, int lane, const float* PV, const float2* ML,
                              const int* OIDX, ushort_t* ATTh) {
    const int bh = row >> 10, i = row & (LQ - 1);
    const size_t p0 = (size_t)bh * RR, p1 = p0 + 1;
    const int s0 = OIDX[p0 * LQ + i];
    const int s1 = OIDX[p1 * LQ + i];
    const float2 ml0 = ML[p0 * LQ + s0];
    const float2 ml1 = ML[p1 * LQ + s1];
    const float M = fmaxf(ml0.x, ml1.x);
    const float w0 = expf(ml0.x - M);
    const float w1 = expf(ml1.x - M);
    const float denom = w0 * ml0.y + w1 * ml1.y;
    const float pv0 = PV[((p0 * LQ + s0) << 6) + lane];
    const float pv1 = PV[((p1 * LQ + s1) << 6) + lane];
    ATTh[(size_t)i * DD + bh * DK + lane] = bfh((w0 * pv0 + w1 * pv1) / denom);
}

// ================= cooperative mega-kernel =================

struct MegaArgs {
    const float *query, *value, *Wq, *bq, *Wv, *bv, *Wo, *bo, *rnd;
    ushort_t *Qh, *Qm, *Ql, *Vh, *WqTh, *WqTm, *WqTl, *WvTh, *WoTh;
    float *Qf, *Vf, *RNORM;
    int *HASH, *HIDX, *OIDX, *HSORT;
    float *PV; float2 *ML; ushort_t *ATTh; float *OUT;
};

__global__ __launch_bounds__(256) void mega_kernel(MegaArgs a) {
    __shared__ __align__(16) char SM[39424];
    cg::grid_group gg = cg::this_grid();
    const int b = blockIdx.x;
    const int tid = threadIdx.x;
    // P0: prep (1280 units)
    for (int u = b; u < 1280; u += NBLK)
        prep_logic(u, SM, a.query, a.value, a.Wq, a.Wv, a.Wo,
                   a.Qh, a.Qm, a.Ql, a.Vh, a.WqTh, a.WqTm, a.WqTl, a.WvTh, a.WoTh);
    gg.sync();
    // P1: qv projections (256 units)
    if (b < 128) {
        int m0 = (b >> 3) * 64, n0 = (b & 7) * 64;
        gemm_core<3>(a.Qh, a.Qm, a.Ql, a.WqTh, a.WqTm, a.WqTl, a.bq, a.Qf, m0, n0, LQ, DK, SM);
    } else if (b < 256) {
        int bb = b - 128;
        int m0 = (bb >> 3) * 64, n0 = (bb & 7) * 64;
        gemm_core<1>(a.Vh, a.Vh, a.Vh, a.WvTh, a.WvTh, a.WvTh, a.bv, a.Vf, m0, n0, LQ, DK, SM);
    }
    gg.sync();
    // P2: hash (512 blocks x 16 rows)
    hash_logic(b, 4, SM, a.Qf, a.rnd, a.HASH, a.RNORM);
    gg.sync();
    // P3: sort (16 pairs)
    if (b < 16) sort_logic(b, SM, a.HASH, a.HIDX, a.OIDX, a.HSORT);
    gg.sync();
    // P4: scores+softmax+PV (512 units)
    spv_logic(b & 31, (b >> 5) & 1, b >> 6, SM, a.Qf, a.RNORM, a.Vf,
              a.HIDX, a.OIDX, a.HSORT, a.PV, a.ML);
    gg.sync();
    // P5: combine (512 blocks x 16 rows)
    {
        const int w = tid >> 6, lane = tid & 63;
        for (int it = 0; it < 4; ++it)
            combine_logic(b * 16 + it * 4 + w, lane, a.PV, a.ML, a.OIDX, a.ATTh);
    }
    gg.sync();
    // P6: output projection (128 units)
    if (b < 128) {
        int m0 = (b >> 3) * 64, n0 = (b & 7) * 64;
        gemm_core<1>(a.ATTh, a.ATTh, a.ATTh, a.WoTh, a.WoTh, a.WoTh, a.bo, a.OUT, m0, n0, 1, DD, SM);
    }
}

// ================= fallback standalone kernels =================

__global__ __launch_bounds__(256) void prep_kernel(const float* query, const float* value,
                                                   const float* Wq, const float* Wv, const float* Wo,
                                                   ushort_t* Qh, ushort_t* Qm, ushort_t* Ql, ushort_t* Vh,
                                                   ushort_t* WqTh, ushort_t* WqTm, ushort_t* WqTl,
                                                   ushort_t* WvTh, ushort_t* WoTh) {
    __shared__ __align__(16) char SM[4224];
    prep_logic(blockIdx.x, SM, query, value, Wq, Wv, Wo, Qh, Qm, Ql, Vh, WqTh, WqTm, WqTl, WvTh, WoTh);
}

__global__ __launch_bounds__(256) void qv_mfma(const ushort_t* Qh, const ushort_t* Qm, const ushort_t* Ql,
                                               const ushort_t* WqTh, const ushort_t* WqTm, const ushort_t* WqTl,
                                               const ushort_t* Vh, const ushort_t* WvTh,
                                               const float* bq, const float* bv,
                                               float* Qf, float* Vf) {
    __shared__ __align__(16) char SM[24576];
    const int b = blockIdx.x;
    if (b < 128) {
        int m0 = (b >> 3) * 64, n0 = (b & 7) * 64;
        gemm_core<3>(Qh, Qm, Ql, WqTh, WqTm, WqTl, bq, Qf, m0, n0, LQ, DK, SM);
    } else {
        int bb = b - 128;
        int m0 = (bb >> 3) * 64, n0 = (bb & 7) * 64;
        gemm_core<1>(Vh, Vh, Vh, WvTh, WvTh, WvTh, bv, Vf, m0, n0, LQ, DK, SM);
    }
}

__global__ __launch_bounds__(256) void hash_kernel(const float* Q, const float* rnd,
                                                   int* HASH, float* RNORM) {
    __shared__ __align__(16) char SM[16384];
    hash_logic(blockIdx.x, 8, SM, Q, rnd, HASH, RNORM);
}

__global__ __launch_bounds__(256) void sort_kernel(const int* HASH, int* HIDX, int* OIDX, int* HSORT) {
    __shared__ __align__(16) char SM[39424];
    sort_logic(blockIdx.x, SM, HASH, HIDX, OIDX, HSORT);
}

__global__ __launch_bounds__(256) void spv_kernel(const float* Q, const float* RNORM, const float* Vf,
                                                  const int* HIDX, const int* OIDX, const int* HSORT,
                                                  float* PV, float2* ML) {
    __shared__ __align__(16) char SM[37440];
    spv_logic(blockIdx.x, blockIdx.y, blockIdx.z, SM, Q, RNORM, Vf, HIDX, OIDX, HSORT, PV, ML);
}

__global__ __launch_bounds__(256) void combine_kernel(const float* PV, const float2* ML,
                                                      const int* OIDX, ushort_t* ATTh) {
    combine_logic(blockIdx.x * 4 + (threadIdx.x >> 6), threadIdx.x & 63, PV, ML, OIDX, ATTh);
}

__global__ __launch_bounds__(256) void out_mfma(const ushort_t* Ah, const ushort_t* WoTh,
                                                const float* bo, float* out) {
    __shared__ __align__(16) char SM[8192];
    const int b = blockIdx.x;
    int m0 = (b >> 3) * 64, n0 = (b & 7) * 64;
    gemm_core<1>(Ah, Ah, Ah, WoTh, WoTh, WoTh, bo, out, m0, n0, 1, DD, SM);
}

// ================= launch =================

extern "C" void kernel_launch(void* const* d_in, const int* in_sizes, int n_in,
                              void* d_out, int out_size, void* d_ws, size_t ws_size,
                              hipStream_t stream) {
    const float* query = (const float*)d_in[0];
    const float* value = (const float*)d_in[2];
    const float* Wq = (const float*)d_in[4];
    const float* bq = (const float*)d_in[5];
    const float* Wv = (const float*)d_in[6];
    const float* bv = (const float*)d_in[7];
    const float* Wo = (const float*)d_in[8];
    const float* bo = (const float*)d_in[9];
    const float* rnd = (const float*)d_in[10];

    char* ws = (char*)d_ws;
    const size_t MB1 = 1u << 20;
    const size_t HK = 512u << 10;
    float*    Qf    = (float*)(ws);                       // [0,2MB)
    float*    Vf    = (float*)(ws + 2 * MB1);             // [2,4MB)
    float*    PV    = (float*)(ws + 4 * MB1);             // [4,8MB)  (phase B)
    ushort_t* ATTh  = (ushort_t*)(ws + 8 * MB1);          // [8,9MB)
    ushort_t* Qh    = (ushort_t*)(ws + 4 * MB1);          // phase A overlays
    ushort_t* Qm    = (ushort_t*)(ws + 5 * MB1);
    ushort_t* Ql    = (ushort_t*)(ws + 6 * MB1);
    ushort_t* WqTh  = (ushort_t*)(ws + 7 * MB1);
    ushort_t* WqTm  = (ushort_t*)(ws + 7 * MB1 + HK);
    ushort_t* WqTl  = (ushort_t*)(ws + 8 * MB1);
    ushort_t* Vh    = (ushort_t*)(ws + 8 * MB1 + HK);
    ushort_t* WvTh  = (ushort_t*)(ws + 9 * MB1 + HK);
    ushort_t* WoTh  = (ushort_t*)(ws + 10 * MB1);         // persistent tail
    float*    RNORM = (float*)(ws + 10 * MB1 + HK);
    char*     tail  = ws + 10 * MB1 + HK + (64u << 10);
    int* HASH  = (int*)(tail);
    int* HIDX  = (int*)(tail + (64u << 10));
    int* OIDX  = (int*)(tail + (128u << 10));
    int* HSORT = (int*)(tail + (192u << 10));
    float2* ML = (float2*)(tail + (256u << 10));
    float* OUT = (float*)d_out;

    MegaArgs a;
    a.query = query; a.value = value; a.Wq = Wq; a.bq = bq; a.Wv = Wv; a.bv = bv;
    a.Wo = Wo; a.bo = bo; a.rnd = rnd;
    a.Qh = Qh; a.Qm = Qm; a.Ql = Ql; a.Vh = Vh;
    a.WqTh = WqTh; a.WqTm = WqTm; a.WqTl = WqTl; a.WvTh = WvTh; a.WoTh = WoTh;
    a.Qf = Qf; a.Vf = Vf; a.RNORM = RNORM;
    a.HASH = HASH; a.HIDX = HIDX; a.OIDX = OIDX; a.HSORT = HSORT;
    a.PV = PV; a.ML = ML; a.ATTh = ATTh; a.OUT = OUT;

    void* kp[] = { (void*)&a };
    hipError_t err = hipLaunchCooperativeKernel((const void*)mega_kernel,
                                                dim3(NBLK), dim3(256), kp, 0u, stream);
    if (err != hipSuccess) {
        // fallback: 7-kernel pipeline (identical math)
        prep_kernel<<<1280, 256, 0, stream>>>(query, value, Wq, Wv, Wo,
                                              Qh, Qm, Ql, Vh, WqTh, WqTm, WqTl, WvTh, WoTh);
        qv_mfma<<<256, 256, 0, stream>>>(Qh, Qm, Ql, WqTh, WqTm, WqTl, Vh, WvTh, bq, bv, Qf, Vf);
        hash_kernel<<<256, 256, 0, stream>>>(Qf, rnd, HASH, RNORM);
        sort_kernel<<<16, 256, 0, stream>>>(HASH, HIDX, OIDX, HSORT);
        spv_kernel<<<dim3(32, 2, 8), 256, 0, stream>>>(Qf, RNORM, Vf, HIDX, OIDX, HSORT, PV, ML);
        combine_kernel<<<2048, 256, 0, stream>>>(PV, ML, OIDX, ATTh);
        out_mfma<<<128, 256, 0, stream>>>(ATTh, WoTh, bo, OUT);
    }
}

// Round 7
// 103.395 us; speedup vs baseline: 4.1269x; 4.1269x over previous
//
#include <hip/hip_runtime.h>
#include <math.h>

#define LQ 1024
#define DD 512
#define DK 64
#define RR 2

typedef unsigned short ushort_t;
typedef __attribute__((ext_vector_type(8))) short bf16x8;
typedef __attribute__((ext_vector_type(4))) float f32x4;

__device__ inline ushort_t bfh(float x) {
    union { float f; unsigned int u; } c; c.f = x;
    unsigned int u = c.u;
    unsigned int r = u + 0x7fffu + ((u >> 16) & 1u);
    return (ushort_t)(r >> 16);
}
__device__ inline float bf2f(ushort_t h) {
    union { unsigned int u; float f; } c; c.u = ((unsigned int)h) << 16;
    return c.f;
}
__device__ inline void store8u(ushort_t* p, const ushort_t h[8]) {
    uint4 v;
    v.x = h[0] | ((unsigned int)h[1] << 16); v.y = h[2] | ((unsigned int)h[3] << 16);
    v.z = h[4] | ((unsigned int)h[5] << 16); v.w = h[6] | ((unsigned int)h[7] << 16);
    *(uint4*)p = v;
}
__device__ inline void store4u(ushort_t* p, const ushort_t h[4]) {
    uint2 v;
    v.x = h[0] | ((unsigned int)h[1] << 16); v.y = h[2] | ((unsigned int)h[3] << 16);
    *(uint2*)p = v;
}

// ---------------- K0: weight transposes only (Wq 3-level, Wv/Wo 1-level) ----------------
__global__ __launch_bounds__(256) void prep_w(const float* __restrict__ Wq,
                                              const float* __restrict__ Wv,
                                              const float* __restrict__ Wo,
                                              ushort_t* __restrict__ WqTh, ushort_t* __restrict__ WqTm,
                                              ushort_t* __restrict__ WqTl,
                                              ushort_t* __restrict__ WvTh, ushort_t* __restrict__ WoTh) {
    __shared__ float tl[32][33];
    const int tid = threadIdx.x;
    const int b = blockIdx.x;
    const int mat = b >> 8;                // 0 Wq, 1 Wv, 2 Wo
    const int tile = b & 255;
    const int r0 = (tile >> 4) * 32;       // k rows
    const int c0 = (tile & 15) * 32;       // n cols
    const float* W = (mat == 0) ? Wq : ((mat == 1) ? Wv : Wo);
    const int rr = tid >> 3, cc = (tid & 7) * 4;
    *(float4*)&tl[rr][cc] = *(const float4*)(W + (size_t)(r0 + rr) * DD + c0 + cc);
    __syncthreads();
    float y[4];
#pragma unroll
    for (int i = 0; i < 4; ++i) y[i] = tl[cc + i][rr];
    size_t ob = (size_t)(c0 + rr) * DD + r0 + cc;
    if (mat == 0) {
        ushort_t h[4], m[4], l[4];
#pragma unroll
        for (int i = 0; i < 4; ++i) {
            h[i] = bfh(y[i]);
            float r1 = y[i] - bf2f(h[i]);
            m[i] = bfh(r1);
            l[i] = bfh(r1 - bf2f(m[i]));
        }
        store4u(WqTh + ob, h); store4u(WqTm + ob, m); store4u(WqTl + ob, l);
    } else {
        ushort_t h[4];
#pragma unroll
        for (int i = 0; i < 4; ++i) h[i] = bfh(y[i]);
        store4u((mat == 1 ? WvTh : WoTh) + ob, h);
    }
}

// ---------------- K1: Q(6-pass)+V(1-pass) projections with on-the-fly split; Q fuses hash ----------------
__global__ __launch_bounds__(256) void qv_hash(const float* __restrict__ query,
                                               const float* __restrict__ value,
                                               const ushort_t* __restrict__ WqTh, const ushort_t* __restrict__ WqTm,
                                               const ushort_t* __restrict__ WqTl, const ushort_t* __restrict__ WvTh,
                                               const float* __restrict__ bq, const float* __restrict__ bv,
                                               const float* __restrict__ rnd,
                                               float* __restrict__ Qf, float* __restrict__ Vf,
                                               int* __restrict__ HASH, float* __restrict__ RNORM) {
    __shared__ __align__(16) char SM[33024];
    const int tid = threadIdx.x;
    const int b = blockIdx.x;
    const int wave = tid >> 6, lane = tid & 63;
    const int wm = wave >> 1, wn = wave & 1;
    const int srow = tid >> 2, skb = tid & 3;
    const int sswz = skb ^ ((srow >> 1) & 3);
    const int lofs = srow * 64 + sswz * 16;
    const int kbr = lane >> 4;
    int aoff[2], boff[2];
#pragma unroll
    for (int f = 0; f < 2; ++f) {
        int ra = wm * 32 + f * 16 + (lane & 15);
        int rb = wn * 32 + f * 16 + (lane & 15);
        aoff[f] = ra * 64 + ((kbr ^ ((ra >> 1) & 3)) << 4);
        boff[f] = rb * 64 + ((kbr ^ ((rb >> 1) & 3)) << 4);
    }
    const bool isQ = (b < 128);
    const int bb = isQ ? b : b - 128;
    const int m0 = (bb >> 3) * 64, n0 = (bb & 7) * 64;
    f32x4 acc[2][2] = {};
    const size_t gA = (size_t)(m0 + srow) * DD + skb * 8;
    const size_t gB = (size_t)(n0 + srow) * DD + skb * 8;
    if (isQ) {
        for (int kt = 0; kt < DD; kt += 32) {
            __syncthreads();
            float x[8];
            *(float4*)&x[0] = *(const float4*)(query + gA + kt);
            *(float4*)&x[4] = *(const float4*)(query + gA + kt + 4);
            ushort_t h[8], mm[8], ll[8];
#pragma unroll
            for (int i = 0; i < 8; ++i) {
                h[i] = bfh(x[i]);
                float r1 = x[i] - bf2f(h[i]);
                mm[i] = bfh(r1);
                ll[i] = bfh(r1 - bf2f(mm[i]));
            }
            store8u((ushort_t*)(SM + lofs), h);
            store8u((ushort_t*)(SM + 4096 + lofs), mm);
            store8u((ushort_t*)(SM + 8192 + lofs), ll);
            *(uint4*)(SM + 12288 + lofs) = *(const uint4*)(WqTh + gB + kt);
            *(uint4*)(SM + 16384 + lofs) = *(const uint4*)(WqTm + gB + kt);
            *(uint4*)(SM + 20480 + lofs) = *(const uint4*)(WqTl + gB + kt);
            __syncthreads();
            bf16x8 af[2][3], bfr[2][3];
#pragma unroll
            for (int f = 0; f < 2; ++f)
#pragma unroll
                for (int lev = 0; lev < 3; ++lev) {
                    af[f][lev] = *(const bf16x8*)(SM + lev * 4096 + aoff[f]);
                    bfr[f][lev] = *(const bf16x8*)(SM + (3 + lev) * 4096 + boff[f]);
                }
#pragma unroll
            for (int i = 0; i < 2; ++i)
#pragma unroll
                for (int j = 0; j < 2; ++j)
#pragma unroll
                    for (int la = 0; la < 3; ++la)
#pragma unroll
                        for (int lb = 0; lb < 3; ++lb)
                            if (la + lb <= 2)
                                acc[i][j] = __builtin_amdgcn_mfma_f32_16x16x32_bf16(
                                    af[i][la], bfr[j][lb], acc[i][j], 0, 0, 0);
        }
    } else {
        for (int kt = 0; kt < DD; kt += 32) {
            __syncthreads();
            float x[8];
            *(float4*)&x[0] = *(const float4*)(value + gA + kt);
            *(float4*)&x[4] = *(const float4*)(value + gA + kt + 4);
            ushort_t h[8];
#pragma unroll
            for (int i = 0; i < 8; ++i) h[i] = bfh(x[i]);
            store8u((ushort_t*)(SM + lofs), h);
            *(uint4*)(SM + 4096 + lofs) = *(const uint4*)(WvTh + gB + kt);
            __syncthreads();
            bf16x8 af[2], bfr[2];
#pragma unroll
            for (int f = 0; f < 2; ++f) {
                af[f] = *(const bf16x8*)(SM + aoff[f]);
                bfr[f] = *(const bf16x8*)(SM + 4096 + boff[f]);
            }
#pragma unroll
            for (int i = 0; i < 2; ++i)
#pragma unroll
                for (int j = 0; j < 2; ++j)
                    acc[i][j] = __builtin_amdgcn_mfma_f32_16x16x32_bf16(af[i], bfr[j], acc[i][j], 0, 0, 0);
        }
    }
    // epilogue: store projections; Q path also fills qtile for fused hash
    const float* bias = isQ ? bq : bv;
    float* outp = isQ ? Qf : Vf;
    float (*qtile)[65] = (float(*)[65])SM;
    __syncthreads();                      // all LDS fragment reads done
#pragma unroll
    for (int i = 0; i < 2; ++i)
#pragma unroll
        for (int j = 0; j < 2; ++j) {
            int cl = wn * 32 + j * 16 + (lane & 15);
            float bb_ = bias[n0 + cl];
#pragma unroll
            for (int reg = 0; reg < 4; ++reg) {
                int rl = wm * 32 + i * 16 + (lane >> 4) * 4 + reg;
                float v = acc[i][j][reg] + bb_;
                outp[(size_t)n0 * LQ + (size_t)(m0 + rl) * DK + cl] = v;
                if (isQ) qtile[rl][cl] = v;
            }
        }
    if (!isQ) return;
    // ---- fused hash: rnorm + projections + argmax, bit-identical to standalone ----
    float (*rmn)[64] = (float(*)[64])(SM + 16640);
    for (int idx = tid; idx < 4096; idx += 256)
        rmn[idx >> 6][idx & 63] = rnd[idx];
    __syncthreads();
    if (tid < 128) {
        int d = tid >> 1, rh = tid & 1;
        float s = 0.f;
        for (int j = 0; j < 32; ++j) { float x = rmn[d][rh * 32 + j]; s += x * x; }
        float nrm = sqrtf(s);
        for (int j = 0; j < 32; ++j) rmn[d][rh * 32 + j] = rmn[d][rh * 32 + j] / nrm;
    }
    __syncthreads();
    const int j = lane & 31, r = lane >> 5;
    const int bh = n0 >> 6;
    for (int it = 0; it < 16; ++it) {
        const int rl = it * 4 + wave;
        float x = qtile[rl][lane];
        float s2 = x * x;
#pragma unroll
        for (int m = 1; m < 64; m <<= 1) s2 += __shfl_xor(s2, m);
        if (lane == 0) RNORM[(size_t)bh * LQ + m0 + rl] = 1.0f / sqrtf(s2);
        float p0 = 0.f, p1 = 0.f, p2 = 0.f, p3 = 0.f;
#pragma unroll 4
        for (int d = 0; d < 64; d += 4) {
            p0 += __shfl(x, d + 0) * rmn[d + 0][lane];
            p1 += __shfl(x, d + 1) * rmn[d + 1][lane];
            p2 += __shfl(x, d + 2) * rmn[d + 2][lane];
            p3 += __shfl(x, d + 3) * rmn[d + 3][lane];
        }
        float p = (p0 + p1) + (p2 + p3);
        float bv_; int bi;
        if (p >= -p) { bv_ = p; bi = j; } else { bv_ = -p; bi = 32 + j; }
#pragma unroll
        for (int m = 1; m < 32; m <<= 1) {
            float ov = __shfl_xor(bv_, m);
            int oi = __shfl_xor(bi, m);
            if (ov > bv_ || (ov == bv_ && oi < bi)) { bv_ = ov; bi = oi; }
        }
        if (j == 0) HASH[((size_t)bh * RR + r) * LQ + m0 + rl] = bi;
    }
}

// ---------------- K2: stable counting sort per (bh, r) ----------------
__global__ __launch_bounds__(256) void sort_kernel(const int* __restrict__ HASH,
                                                   int* __restrict__ HIDX,
                                                   int* __restrict__ OIDX,
                                                   int* __restrict__ HSORT) {
    __shared__ __align__(16) char SM[39424];
    int* hl = (int*)SM;
    ushort_t (*cnt)[64] = (ushort_t(*)[64])(SM + 4096);
    int (*psum)[4] = (int(*)[4])(SM + 36864);
    int (*poff)[4] = (int(*)[4])(SM + 37888);
    int* base = (int*)(SM + 38912);
    const int tid = threadIdx.x;
    const int pair = blockIdx.x;
    const int* hsrc = HASH + (size_t)pair * LQ;
    for (int i = tid; i < 1024; i += 256) hl[i] = hsrc[i];
    int* cz = (int*)(SM + 4096);
    for (int i = tid; i < 8192; i += 256) cz[i] = 0;
    __syncthreads();
    for (int i = 0; i < 4; ++i) {
        int h = hl[tid * 4 + i];
        cnt[tid][h] += 1;
    }
    __syncthreads();
    {
        int h = tid >> 2, seg = tid & 3;
        int run = 0;
        for (int tt = seg * 64; tt < seg * 64 + 64; ++tt) {
            int tmp = cnt[tt][h];
            cnt[tt][h] = (ushort_t)run;
            run += tmp;
        }
        psum[h][seg] = run;
    }
    __syncthreads();
    if (tid < 64) {
        int run = 0;
#pragma unroll
        for (int seg = 0; seg < 4; ++seg) { int t = psum[tid][seg]; poff[tid][seg] = run; run += t; }
        int incl = run;
#pragma unroll
        for (int d = 1; d < 64; d <<= 1) {
            int y = __shfl_up(incl, d);
            if (tid >= d) incl += y;
        }
        base[tid] = incl - run;
    }
    __syncthreads();
    int* HI = HIDX + (size_t)pair * LQ;
    int* OI = OIDX + (size_t)pair * LQ;
    int* HS = HSORT + (size_t)pair * LQ;
    const int myseg = tid >> 6;
    for (int i = 0; i < 4; ++i) {
        int l = tid * 4 + i;
        int h = hl[l];
        int pos = base[h] + poff[h][myseg] + cnt[tid][h];
        cnt[tid][h] = (ushort_t)(cnt[tid][h] + 1);
        HI[pos] = l;
        OI[l] = pos;
        HS[pos] = h;
    }
}

// ---------------- K3: fused scores + per-pair softmax partials + PV ----------------
__global__ __launch_bounds__(256) void spv_kernel(const float* __restrict__ Q,
                                                  const float* __restrict__ RNORM,
                                                  const float* __restrict__ Vf,
                                                  const int* __restrict__ HIDX,
                                                  const int* __restrict__ OIDX,
                                                  const int* __restrict__ HSORT,
                                                  float* __restrict__ PV,
                                                  float2* __restrict__ ML) {
    const int n = blockIdx.x, r = blockIdx.y, bh = blockIdx.z;
    const int pair = bh * RR + r;
    __shared__ __align__(16) char SM[37440];
    float (*Qs)[65] = (float(*)[65])SM;
    float (*Ks)[65] = (float(*)[65])(SM + 8320);
    float (*Vt)[68] = (float(*)[68])SM;
    float (*Pl)[68] = (float(*)[68])(SM + 25024);
    float (*redm)[8] = (float(*)[8])(SM + 33728);
    float (*redl)[8] = (float(*)[8])(SM + 34752);
    int* qi_l = (int*)(SM + 35776);
    int* hsq  = (int*)(SM + 35904);
    int* Aq   = (int*)(SM + 36032);
    int* ki_l = (int*)(SM + 36160);
    int* hsk  = (int*)(SM + 36416);
    int* Ak   = (int*)(SM + 36672);
    float* krn  = (float*)(SM + 36928);
    float* lcnt = (float*)(SM + 37184);
    const int tid = threadIdx.x;
    const int* HI = HIDX + (size_t)pair * LQ;
    const int* OI = OIDX + (size_t)pair * LQ;
    const int* HS = HSORT + (size_t)pair * LQ;
    if (tid < 32) {
        int s = n * 32 + tid;
        qi_l[tid] = HI[s]; hsq[tid] = HS[s]; Aq[tid] = OI[s];
    } else if (tid < 96) {
        int k = tid - 32;
        int t = (n - 1) * 32 + k;
        if (t < 0) { ki_l[k] = -1; hsk[k] = 0; Ak[k] = 0; krn[k] = 0.f; }
        else {
            int ki = HI[t];
            ki_l[k] = ki; hsk[k] = HS[t]; Ak[k] = OI[t];
            krn[k] = RNORM[(size_t)bh * LQ + ki];
        }
    }
    __syncthreads();
    if (tid == 0) {
        if (n > 0) {
            for (int k = 0; k < 64; ++k) lcnt[k] = 0.f;
        } else {
            int zc = 0;
            for (int k = 32; k < 64; ++k) zc += (Ak[k] == 0);
            float l32 = logf((float)(32 + zc));
            for (int k = 0; k < 32; ++k) lcnt[k] = l32;
            for (int k = 32; k < 64; ++k) lcnt[k] = (Ak[k] == 0) ? l32 : 0.f;
        }
    }
    for (int idx = tid; idx < 32 * 16; idx += 256) {
        int row = idx >> 4, c4 = idx & 15;
        float4 v = ((const float4*)(Q + ((size_t)bh * LQ + qi_l[row]) * DK))[c4];
        Qs[row][c4 * 4 + 0] = v.x; Qs[row][c4 * 4 + 1] = v.y;
        Qs[row][c4 * 4 + 2] = v.z; Qs[row][c4 * 4 + 3] = v.w;
    }
    for (int idx = tid; idx < 64 * 16; idx += 256) {
        int row = idx >> 4, c4 = idx & 15;
        int ki = ki_l[row];
        float4 v;
        if (ki < 0) { v.x = 0.f; v.y = 0.f; v.z = 0.f; v.w = 0.f; }
        else {
            v = ((const float4*)(Q + ((size_t)bh * LQ + ki) * DK))[c4];
            float rn = krn[row];
            v.x *= rn; v.y *= rn; v.z *= rn; v.w *= rn;
        }
        Ks[row][c4 * 4 + 0] = v.x; Ks[row][c4 * 4 + 1] = v.y;
        Ks[row][c4 * 4 + 2] = v.z; Ks[row][c4 * 4 + 3] = v.w;
    }
    __syncthreads();
    const int qq = tid & 31;
    const int g = tid >> 5;
    const int k0 = g * 8;
    float acc[8] = {};
    for (int d = 0; d < 64; ++d) {
        float qv = Qs[qq][d];
#pragma unroll
        for (int kk = 0; kk < 8; ++kk) acc[kk] += qv * Ks[k0 + kk][d];
    }
    const int s = n * 32 + qq;
    const int aq = Aq[qq], hq = hsq[qq];
    float sc[8];
    float pm = -3.4e38f;
#pragma unroll
    for (int kk = 0; kk < 8; ++kk) {
        int k = k0 + kk;
        float v = acc[kk] * 0.125f;
        v = v - ((n == 0 && k < 32) ? 1e9f : 0.f);
        v = v - ((hq == hsk[k]) ? 0.f : 1e9f);
        v = v - ((aq > Ak[k]) ? 0.f : 1e9f);
        v = v - ((aq == Ak[k]) ? 1e5f : 0.f);
        v = v - lcnt[k];
        sc[kk] = v;
        pm = fmaxf(pm, v);
    }
    redm[qq][g] = pm;
    __syncthreads();
    for (int idx = tid; idx < 64 * 16; idx += 256) {
        int row = idx >> 4, c4 = idx & 15;
        int ki = ki_l[row];
        float4 v;
        if (ki < 0) { v.x = 0.f; v.y = 0.f; v.z = 0.f; v.w = 0.f; }
        else v = ((const float4*)(Vf + ((size_t)bh * LQ + ki) * DK))[c4];
        Vt[c4 * 4 + 0][row] = v.x; Vt[c4 * 4 + 1][row] = v.y;
        Vt[c4 * 4 + 2][row] = v.z; Vt[c4 * 4 + 3][row] = v.w;
    }
    float m = redm[qq][0];
#pragma unroll
    for (int t = 1; t < 8; ++t) m = fmaxf(m, redm[qq][t]);
    float psum = 0.f;
#pragma unroll
    for (int kk = 0; kk < 8; ++kk) {
        float e = expf(sc[kk] - m);
        Pl[qq][k0 + kk] = e;
        psum += e;
    }
    redl[qq][g] = psum;
    __syncthreads();
    float lsum = redl[qq][0];
#pragma unroll
    for (int t = 1; t < 8; ++t) lsum += redl[qq][t];
    float o[8] = {};
    for (int k4 = 0; k4 < 16; ++k4) {
        float4 p4 = *(const float4*)&Pl[qq][k4 * 4];
        float pv[4] = {p4.x, p4.y, p4.z, p4.w};
#pragma unroll
        for (int dd = 0; dd < 8; ++dd) {
            float4 v4 = *(const float4*)&Vt[k0 + dd][k4 * 4];
            o[dd] += pv[0] * v4.x + pv[1] * v4.y + pv[2] * v4.z + pv[3] * v4.w;
        }
    }
    float* dst = PV + (((size_t)pair * LQ + s) << 6) + k0;
    float4 o0, o1;
    o0.x = o[0]; o0.y = o[1]; o0.z = o[2]; o0.w = o[3];
    o1.x = o[4]; o1.y = o[5]; o1.z = o[6]; o1.w = o[7];
    *(float4*)dst = o0; *(float4*)(dst + 4) = o1;
    if (g == 0) ML[(size_t)pair * LQ + s] = make_float2(m, lsum);
}

// ---------------- K4: output projection with fused combine in A-staging ----------------
__global__ __launch_bounds__(256) void out_combine(const float* __restrict__ PV,
                                                   const float2* __restrict__ ML,
                                                   const int* __restrict__ OIDX,
                                                   const ushort_t* __restrict__ WoTh,
                                                   const float* __restrict__ bo,
                                                   float* __restrict__ out) {
    __shared__ __align__(16) char SM[8192];
    const int tid = threadIdx.x;
    const int b = blockIdx.x;
    const int wave = tid >> 6, lane = tid & 63;
    const int wm = wave >> 1, wn = wave & 1;
    const int srow = tid >> 2, skb = tid & 3;
    const int sswz = skb ^ ((srow >> 1) & 3);
    const int lofs = srow * 64 + sswz * 16;
    const int kbr = lane >> 4;
    int aoff[2], boff[2];
#pragma unroll
    for (int f = 0; f < 2; ++f) {
        int ra = wm * 32 + f * 16 + (lane & 15);
        int rb = wn * 32 + f * 16 + (lane & 15);
        aoff[f] = ra * 64 + ((kbr ^ ((ra >> 1) & 3)) << 4);
        boff[f] = rb * 64 + ((kbr ^ ((rb >> 1) & 3)) << 4);
    }
    const int m0 = (b >> 3) * 64, n0 = (b & 7) * 64;
    const int l = m0 + srow;
    const size_t gB = (size_t)(n0 + srow) * DD + skb * 8;
    f32x4 acc[2][2] = {};
    for (int kt = 0; kt < DD; kt += 32) {
        __syncthreads();
        const int c0 = kt + skb * 8;
        const int bh = c0 >> 6, d0 = c0 & 63;
        const size_t p0 = (size_t)bh * RR;
        const int s0 = OIDX[p0 * LQ + l];
        const int s1 = OIDX[(p0 + 1) * LQ + l];
        const float2 ml0 = ML[p0 * LQ + s0];
        const float2 ml1 = ML[(p0 + 1) * LQ + s1];
        const float M = fmaxf(ml0.x, ml1.x);
        const float w0 = expf(ml0.x - M);
        const float w1 = expf(ml1.x - M);
        const float denom = w0 * ml0.y + w1 * ml1.y;
        const float* q0 = PV + ((p0 * LQ + s0) << 6) + d0;
        const float* q1 = PV + (((p0 + 1) * LQ + s1) << 6) + d0;
        float a0[8], a1[8];
        *(float4*)&a0[0] = *(const float4*)q0; *(float4*)&a0[4] = *(const float4*)(q0 + 4);
        *(float4*)&a1[0] = *(const float4*)q1; *(float4*)&a1[4] = *(const float4*)(q1 + 4);
        ushort_t hh[8];
#pragma unroll
        for (int d = 0; d < 8; ++d)
            hh[d] = bfh((w0 * a0[d] + w1 * a1[d]) / denom);
        store8u((ushort_t*)(SM + lofs), hh);
        *(uint4*)(SM + 4096 + lofs) = *(const uint4*)(WoTh + gB + kt);
        __syncthreads();
        bf16x8 af[2], bfr[2];
#pragma unroll
        for (int f = 0; f < 2; ++f) {
            af[f] = *(const bf16x8*)(SM + aoff[f]);
            bfr[f] = *(const bf16x8*)(SM + 4096 + boff[f]);
        }
#pragma unroll
        for (int i = 0; i < 2; ++i)
#pragma unroll
            for (int j = 0; j < 2; ++j)
                acc[i][j] = __builtin_amdgcn_mfma_f32_16x16x32_bf16(af[i], bfr[j], acc[i][j], 0, 0, 0);
    }
#pragma unroll
    for (int i = 0; i < 2; ++i)
#pragma unroll
        for (int j = 0; j < 2; ++j) {
            int cl = wn * 32 + j * 16 + (lane & 15);
            float bb_ = bo[n0 + cl];
#pragma unroll
            for (int reg = 0; reg < 4; ++reg) {
                int rl = wm * 32 + i * 16 + (lane >> 4) * 4 + reg;
                out[(size_t)(m0 + rl) * DD + n0 + cl] = acc[i][j][reg] + bb_;
            }
        }
}

extern "C" void kernel_launch(void* const* d_in, const int* in_sizes, int n_in,
                              void* d_out, int out_size, void* d_ws, size_t ws_size,
                              hipStream_t stream) {
    const float* query = (const float*)d_in[0];
    const float* value = (const float*)d_in[2];
    const float* Wq = (const float*)d_in[4];
    const float* bq = (const float*)d_in[5];
    const float* Wv = (const float*)d_in[6];
    const float* bv = (const float*)d_in[7];
    const float* Wo = (const float*)d_in[8];
    const float* bo = (const float*)d_in[9];
    const float* rnd = (const float*)d_in[10];

    char* ws = (char*)d_ws;
    const size_t MB1 = 1u << 20;
    const size_t HK = 512u << 10;
    float*    Qf    = (float*)(ws);                       // [0,2MB)
    float*    Vf    = (float*)(ws + 2 * MB1);             // [2,4MB)
    float*    PV    = (float*)(ws + 4 * MB1);             // [4,8MB)
    ushort_t* WqTh  = (ushort_t*)(ws + 8 * MB1);
    ushort_t* WqTm  = (ushort_t*)(ws + 8 * MB1 + HK);
    ushort_t* WqTl  = (ushort_t*)(ws + 9 * MB1);
    ushort_t* WvTh  = (ushort_t*)(ws + 9 * MB1 + HK);
    ushort_t* WoTh  = (ushort_t*)(ws + 10 * MB1);
    float*    RNORM = (float*)(ws + 10 * MB1 + HK);       // 32KB
    char*     tail  = ws + 10 * MB1 + HK + (64u << 10);
    int* HASH  = (int*)(tail);
    int* HIDX  = (int*)(tail + (64u << 10));
    int* OIDX  = (int*)(tail + (128u << 10));
    int* HSORT = (int*)(tail + (192u << 10));
    float2* ML = (float2*)(tail + (256u << 10));          // 128KB
    float* OUT = (float*)d_out;

    prep_w<<<768, 256, 0, stream>>>(Wq, Wv, Wo, WqTh, WqTm, WqTl, WvTh, WoTh);
    qv_hash<<<256, 256, 0, stream>>>(query, value, WqTh, WqTm, WqTl, WvTh,
                                     bq, bv, rnd, Qf, Vf, HASH, RNORM);
    sort_kernel<<<16, 256, 0, stream>>>(HASH, HIDX, OIDX, HSORT);
    spv_kernel<<<dim3(32, 2, 8), 256, 0, stream>>>(Qf, RNORM, Vf, HIDX, OIDX, HSORT, PV, ML);
    out_combine<<<128, 256, 0, stream>>>(PV, ML, OIDX, WoTh, bo, OUT);
}

// Round 8
// 85.677 us; speedup vs baseline: 4.9803x; 1.2068x over previous
//
#include <hip/hip_runtime.h>
#include <math.h>

#define LQ 1024
#define DD 512
#define DK 64
#define RR 2

typedef unsigned short ushort_t;
typedef __attribute__((ext_vector_type(8))) _Float16 f16x8;
typedef __attribute__((ext_vector_type(4))) float f32x4;

__device__ inline ushort_t f16b(float x) {
    union { _Float16 h; ushort_t u; } c; c.h = (_Float16)x; return c.u;
}
__device__ inline float f16tof(ushort_t u) {
    union { ushort_t u; _Float16 h; } c; c.u = u; return (float)c.h;
}
__device__ inline void store4u(ushort_t* p, const ushort_t h[4]) {
    uint2 v;
    v.x = h[0] | ((unsigned int)h[1] << 16); v.y = h[2] | ((unsigned int)h[3] << 16);
    *(uint2*)p = v;
}

// ---------------- K0: weight transposes (Wq 2-level fp16, Wv/Wo 1-level fp16) ----------------
__global__ __launch_bounds__(256) void prep_w(const float* __restrict__ Wq,
                                              const float* __restrict__ Wv,
                                              const float* __restrict__ Wo,
                                              ushort_t* __restrict__ WqTh, ushort_t* __restrict__ WqTm,
                                              ushort_t* __restrict__ WvTh, ushort_t* __restrict__ WoTh) {
    __shared__ float tl[32][33];
    const int tid = threadIdx.x;
    const int b = blockIdx.x;
    const int mat = b >> 8;                // 0 Wq, 1 Wv, 2 Wo
    const int tile = b & 255;
    const int r0 = (tile >> 4) * 32;       // k rows
    const int c0 = (tile & 15) * 32;       // n cols
    const float* W = (mat == 0) ? Wq : ((mat == 1) ? Wv : Wo);
    const int rr = tid >> 3, cc = (tid & 7) * 4;
    *(float4*)&tl[rr][cc] = *(const float4*)(W + (size_t)(r0 + rr) * DD + c0 + cc);
    __syncthreads();
    float y[4];
#pragma unroll
    for (int i = 0; i < 4; ++i) y[i] = tl[cc + i][rr];
    size_t ob = (size_t)(c0 + rr) * DD + r0 + cc;
    if (mat == 0) {
        ushort_t h[4], m[4];
#pragma unroll
        for (int i = 0; i < 4; ++i) {
            h[i] = f16b(y[i]);
            m[i] = f16b((y[i] - f16tof(h[i])) * 2048.f);
        }
        store4u(WqTh + ob, h); store4u(WqTm + ob, m);
    } else {
        ushort_t h[4];
#pragma unroll
        for (int i = 0; i < 4; ++i) h[i] = f16b(y[i]);
        store4u((mat == 1 ? WvTh : WoTh) + ob, h);
    }
}

// ---------------- K1: all projection GEMM passes, 32x64 tiles, fp16 MFMA, issue-early prefetch ----
// blocks [0,256): Q-hh -> P0 ; [256,512): Q-(hm+mh) -> P1 ; [512,768): V -> Vf (+bias)
__global__ __launch_bounds__(256) void gemm_all(const float* __restrict__ query,
                                                const float* __restrict__ value,
                                                const ushort_t* __restrict__ WqTh,
                                                const ushort_t* __restrict__ WqTm,
                                                const ushort_t* __restrict__ WvTh,
                                                const float* __restrict__ bv,
                                                float* __restrict__ P0, float* __restrict__ P1,
                                                float* __restrict__ Vf) {
    __shared__ __align__(16) char SM[12288];   // Ah@0(2KB) Am@2048 Bh@4096(4KB) Bm@8192(4KB)
    const int tid = threadIdx.x;
    const int b = blockIdx.x;
    const int pass = b >> 8;                   // 0 hh, 1 hm+mh, 2 V
    const int t = b & 255;
    const int m0 = (t >> 3) * 32, n0 = (t & 7) * 64;
    const int wave = tid >> 6, lane = tid & 63;
    const int wm_ = wave & 1, wn_ = wave >> 1;
    // staging coords
    const int arow = tid >> 3;
    const int abyte = arow * 64 + ((((tid & 7) >> 1) ^ (arow & 3)) << 4) + (tid & 1) * 8;
    const int brow = tid >> 2, bs = tid & 3;
    const int bbyte = brow * 64 + ((bs ^ (brow & 3)) << 4);
    const size_t gA = (size_t)(m0 + arow) * DD + (tid & 7) * 4;
    const size_t gB = (size_t)(n0 + brow) * DD + bs * 8;
    // fragment offsets
    const int kb = lane >> 4;
    const int far_ = wm_ * 16 + (lane & 15);
    const int fabyte = far_ * 64 + ((kb ^ (far_ & 3)) << 4);
    int fbbyte[2];
#pragma unroll
    for (int j = 0; j < 2; ++j) {
        int c = wn_ * 32 + j * 16 + (lane & 15);
        fbbyte[j] = c * 64 + ((kb ^ (c & 3)) << 4);
    }
    const float* Asrc = (pass == 2) ? value : query;
    const ushort_t* Bh_src = (pass == 2) ? WvTh : WqTh;
    f32x4 acc[2] = {};
    float4 xa = *(const float4*)(Asrc + gA);
    uint4 wh = *(const uint4*)(Bh_src + gB);
    uint4 wm = {};
    if (pass == 1) wm = *(const uint4*)(WqTm + gB);
    for (int kt = 0; kt < DD; kt += 32) {
        __syncthreads();
        {
            float xs[4] = {xa.x, xa.y, xa.z, xa.w};
            ushort_t h4[4];
#pragma unroll
            for (int i = 0; i < 4; ++i) h4[i] = f16b(xs[i]);
            store4u((ushort_t*)(SM + abyte), h4);
            if (pass == 1) {
                ushort_t m4[4];
#pragma unroll
                for (int i = 0; i < 4; ++i)
                    m4[i] = f16b((xs[i] - f16tof(h4[i])) * 2048.f);
                store4u((ushort_t*)(SM + 2048 + abyte), m4);
            }
            *(uint4*)(SM + 4096 + bbyte) = wh;
            if (pass == 1) *(uint4*)(SM + 8192 + bbyte) = wm;
        }
        __syncthreads();
        if (kt + 32 < DD) {                      // issue-early prefetch (overlaps MFMA below)
            xa = *(const float4*)(Asrc + gA + kt + 32);
            wh = *(const uint4*)(Bh_src + gB + kt + 32);
            if (pass == 1) wm = *(const uint4*)(WqTm + gB + kt + 32);
        }
        f16x8 ah = *(const f16x8*)(SM + fabyte);
        f16x8 bh0 = *(const f16x8*)(SM + 4096 + fbbyte[0]);
        f16x8 bh1 = *(const f16x8*)(SM + 4096 + fbbyte[1]);
        if (pass == 1) {
            f16x8 am = *(const f16x8*)(SM + 2048 + fabyte);
            f16x8 bm0 = *(const f16x8*)(SM + 8192 + fbbyte[0]);
            f16x8 bm1 = *(const f16x8*)(SM + 8192 + fbbyte[1]);
            acc[0] = __builtin_amdgcn_mfma_f32_16x16x32_f16(ah, bm0, acc[0], 0, 0, 0);
            acc[0] = __builtin_amdgcn_mfma_f32_16x16x32_f16(am, bh0, acc[0], 0, 0, 0);
            acc[1] = __builtin_amdgcn_mfma_f32_16x16x32_f16(ah, bm1, acc[1], 0, 0, 0);
            acc[1] = __builtin_amdgcn_mfma_f32_16x16x32_f16(am, bh1, acc[1], 0, 0, 0);
        } else {
            acc[0] = __builtin_amdgcn_mfma_f32_16x16x32_f16(ah, bh0, acc[0], 0, 0, 0);
            acc[1] = __builtin_amdgcn_mfma_f32_16x16x32_f16(ah, bh1, acc[1], 0, 0, 0);
        }
    }
    float* dst = (pass == 0) ? P0 : ((pass == 1) ? P1 : Vf);
#pragma unroll
    for (int j = 0; j < 2; ++j) {
        int cl = wn_ * 32 + j * 16 + (lane & 15);
        float bias_ = (pass == 2) ? bv[n0 + cl] : 0.f;
#pragma unroll
        for (int reg = 0; reg < 4; ++reg) {
            int rl = wm_ * 16 + (lane >> 4) * 4 + reg;
            dst[(size_t)n0 * LQ + (size_t)(m0 + rl) * DK + cl] = acc[j][reg] + bias_;
        }
    }
}

// ---------------- K2: combine partials -> q; rnorm + projections + argmax hashes ----------------
__global__ __launch_bounds__(256) void hash_kernel(const float* __restrict__ P0,
                                                   const float* __restrict__ P1,
                                                   const float* __restrict__ bq,
                                                   const float* __restrict__ rnd,
                                                   float* __restrict__ Qf,
                                                   int* __restrict__ HASH,
                                                   float* __restrict__ RNORM) {
    __shared__ float rmn[64][64];
    const int tid = threadIdx.x;
    for (int idx = tid; idx < 4096; idx += 256)
        rmn[idx >> 6][idx & 63] = rnd[idx];
    __syncthreads();
    if (tid < 128) {
        int d = tid >> 1, rh = tid & 1;
        float s = 0.f;
        for (int j = 0; j < 32; ++j) { float x = rmn[d][rh * 32 + j]; s += x * x; }
        float nrm = sqrtf(s);
        for (int j = 0; j < 32; ++j) rmn[d][rh * 32 + j] = rmn[d][rh * 32 + j] / nrm;
    }
    __syncthreads();
    const int w = tid >> 6, lane = tid & 63;
    const int j = lane & 31, r = lane >> 5;
    const int rowbase = blockIdx.x * 32;
    for (int it = 0; it < 8; ++it) {
        const int row = rowbase + it * 4 + w;
        const int bh = row >> 10, l = row & (LQ - 1);
        const size_t ad = (size_t)row * DK + lane;
        float x = P0[ad] + P1[ad] * (1.f / 2048.f) + bq[(bh << 6) + lane];
        Qf[ad] = x;
        float s2 = x * x;
#pragma unroll
        for (int m = 1; m < 64; m <<= 1) s2 += __shfl_xor(s2, m);
        if (lane == 0) RNORM[row] = 1.0f / sqrtf(s2);
        float p0 = 0.f, p1 = 0.f, p2 = 0.f, p3 = 0.f;
#pragma unroll 4
        for (int d = 0; d < 64; d += 4) {
            p0 += __shfl(x, d + 0) * rmn[d + 0][lane];
            p1 += __shfl(x, d + 1) * rmn[d + 1][lane];
            p2 += __shfl(x, d + 2) * rmn[d + 2][lane];
            p3 += __shfl(x, d + 3) * rmn[d + 3][lane];
        }
        float p = (p0 + p1) + (p2 + p3);
        float bv_; int bi;
        if (p >= -p) { bv_ = p; bi = j; } else { bv_ = -p; bi = 32 + j; }
#pragma unroll
        for (int m = 1; m < 32; m <<= 1) {
            float ov = __shfl_xor(bv_, m);
            int oi = __shfl_xor(bi, m);
            if (ov > bv_ || (ov == bv_ && oi < bi)) { bv_ = ov; bi = oi; }
        }
        if (j == 0) HASH[((size_t)bh * RR + r) * LQ + l] = bi;
    }
}

// ---------------- K3: stable counting sort per (bh, r) ----------------
__global__ __launch_bounds__(256) void sort_kernel(const int* __restrict__ HASH,
                                                   int* __restrict__ HIDX,
                                                   int* __restrict__ OIDX,
                                                   int* __restrict__ HSORT) {
    __shared__ __align__(16) char SM[39424];
    int* hl = (int*)SM;
    ushort_t (*cnt)[64] = (ushort_t(*)[64])(SM + 4096);
    int (*psum)[4] = (int(*)[4])(SM + 36864);
    int (*poff)[4] = (int(*)[4])(SM + 37888);
    int* base = (int*)(SM + 38912);
    const int tid = threadIdx.x;
    const int pair = blockIdx.x;
    const int* hsrc = HASH + (size_t)pair * LQ;
    for (int i = tid; i < 1024; i += 256) hl[i] = hsrc[i];
    int* cz = (int*)(SM + 4096);
    for (int i = tid; i < 8192; i += 256) cz[i] = 0;
    __syncthreads();
    for (int i = 0; i < 4; ++i) {
        int h = hl[tid * 4 + i];
        cnt[tid][h] += 1;
    }
    __syncthreads();
    {
        int h = tid >> 2, seg = tid & 3;
        int run = 0;
        for (int tt = seg * 64; tt < seg * 64 + 64; ++tt) {
            int tmp = cnt[tt][h];
            cnt[tt][h] = (ushort_t)run;
            run += tmp;
        }
        psum[h][seg] = run;
    }
    __syncthreads();
    if (tid < 64) {
        int run = 0;
#pragma unroll
        for (int seg = 0; seg < 4; ++seg) { int t = psum[tid][seg]; poff[tid][seg] = run; run += t; }
        int incl = run;
#pragma unroll
        for (int d = 1; d < 64; d <<= 1) {
            int y = __shfl_up(incl, d);
            if (tid >= d) incl += y;
        }
        base[tid] = incl - run;
    }
    __syncthreads();
    int* HI = HIDX + (size_t)pair * LQ;
    int* OI = OIDX + (size_t)pair * LQ;
    int* HS = HSORT + (size_t)pair * LQ;
    const int myseg = tid >> 6;
    for (int i = 0; i < 4; ++i) {
        int l = tid * 4 + i;
        int h = hl[l];
        int pos = base[h] + poff[h][myseg] + cnt[tid][h];
        cnt[tid][h] = (ushort_t)(cnt[tid][h] + 1);
        HI[pos] = l;
        OI[l] = pos;
        HS[pos] = h;
    }
}

// ---------------- K4: fused scores + per-pair softmax partials + PV ----------------
__global__ __launch_bounds__(256) void spv_kernel(const float* __restrict__ Q,
                                                  const float* __restrict__ RNORM,
                                                  const float* __restrict__ Vf,
                                                  const int* __restrict__ HIDX,
                                                  const int* __restrict__ OIDX,
                                                  const int* __restrict__ HSORT,
                                                  float* __restrict__ PV,
                                                  float2* __restrict__ ML) {
    const int n = blockIdx.x, r = blockIdx.y, bh = blockIdx.z;
    const int pair = bh * RR + r;
    __shared__ __align__(16) char SM[37440];
    float (*Qs)[65] = (float(*)[65])SM;
    float (*Ks)[65] = (float(*)[65])(SM + 8320);
    float (*Vt)[68] = (float(*)[68])SM;
    float (*Pl)[68] = (float(*)[68])(SM + 25024);
    float (*redm)[8] = (float(*)[8])(SM + 33728);
    float (*redl)[8] = (float(*)[8])(SM + 34752);
    int* qi_l = (int*)(SM + 35776);
    int* hsq  = (int*)(SM + 35904);
    int* Aq   = (int*)(SM + 36032);
    int* ki_l = (int*)(SM + 36160);
    int* hsk  = (int*)(SM + 36416);
    int* Ak   = (int*)(SM + 36672);
    float* krn  = (float*)(SM + 36928);
    float* lcnt = (float*)(SM + 37184);
    const int tid = threadIdx.x;
    const int* HI = HIDX + (size_t)pair * LQ;
    const int* OI = OIDX + (size_t)pair * LQ;
    const int* HS = HSORT + (size_t)pair * LQ;
    if (tid < 32) {
        int s = n * 32 + tid;
        qi_l[tid] = HI[s]; hsq[tid] = HS[s]; Aq[tid] = OI[s];
    } else if (tid < 96) {
        int k = tid - 32;
        int t = (n - 1) * 32 + k;
        if (t < 0) { ki_l[k] = -1; hsk[k] = 0; Ak[k] = 0; krn[k] = 0.f; }
        else {
            int ki = HI[t];
            ki_l[k] = ki; hsk[k] = HS[t]; Ak[k] = OI[t];
            krn[k] = RNORM[(size_t)bh * LQ + ki];
        }
    }
    __syncthreads();
    if (tid == 0) {
        if (n > 0) {
            for (int k = 0; k < 64; ++k) lcnt[k] = 0.f;
        } else {
            int zc = 0;
            for (int k = 32; k < 64; ++k) zc += (Ak[k] == 0);
            float l32 = logf((float)(32 + zc));
            for (int k = 0; k < 32; ++k) lcnt[k] = l32;
            for (int k = 32; k < 64; ++k) lcnt[k] = (Ak[k] == 0) ? l32 : 0.f;
        }
    }
    for (int idx = tid; idx < 32 * 16; idx += 256) {
        int row = idx >> 4, c4 = idx & 15;
        float4 v = ((const float4*)(Q + ((size_t)bh * LQ + qi_l[row]) * DK))[c4];
        Qs[row][c4 * 4 + 0] = v.x; Qs[row][c4 * 4 + 1] = v.y;
        Qs[row][c4 * 4 + 2] = v.z; Qs[row][c4 * 4 + 3] = v.w;
    }
    for (int idx = tid; idx < 64 * 16; idx += 256) {
        int row = idx >> 4, c4 = idx & 15;
        int ki = ki_l[row];
        float4 v;
        if (ki < 0) { v.x = 0.f; v.y = 0.f; v.z = 0.f; v.w = 0.f; }
        else {
            v = ((const float4*)(Q + ((size_t)bh * LQ + ki) * DK))[c4];
            float rn = krn[row];
            v.x *= rn; v.y *= rn; v.z *= rn; v.w *= rn;
        }
        Ks[row][c4 * 4 + 0] = v.x; Ks[row][c4 * 4 + 1] = v.y;
        Ks[row][c4 * 4 + 2] = v.z; Ks[row][c4 * 4 + 3] = v.w;
    }
    __syncthreads();
    const int qq = tid & 31;
    const int g = tid >> 5;
    const int k0 = g * 8;
    float acc[8] = {};
    for (int d = 0; d < 64; ++d) {
        float qv = Qs[qq][d];
#pragma unroll
        for (int kk = 0; kk < 8; ++kk) acc[kk] += qv * Ks[k0 + kk][d];
    }
    const int s = n * 32 + qq;
    const int aq = Aq[qq], hq = hsq[qq];
    float sc[8];
    float pm = -3.4e38f;
#pragma unroll
    for (int kk = 0; kk < 8; ++kk) {
        int k = k0 + kk;
        float v = acc[kk] * 0.125f;
        v = v - ((n == 0 && k < 32) ? 1e9f : 0.f);
        v = v - ((hq == hsk[k]) ? 0.f : 1e9f);
        v = v - ((aq > Ak[k]) ? 0.f : 1e9f);
        v = v - ((aq == Ak[k]) ? 1e5f : 0.f);
        v = v - lcnt[k];
        sc[kk] = v;
        pm = fmaxf(pm, v);
    }
    redm[qq][g] = pm;
    __syncthreads();
    for (int idx = tid; idx < 64 * 16; idx += 256) {
        int row = idx >> 4, c4 = idx & 15;
        int ki = ki_l[row];
        float4 v;
        if (ki < 0) { v.x = 0.f; v.y = 0.f; v.z = 0.f; v.w = 0.f; }
        else v = ((const float4*)(Vf + ((size_t)bh * LQ + ki) * DK))[c4];
        Vt[c4 * 4 + 0][row] = v.x; Vt[c4 * 4 + 1][row] = v.y;
        Vt[c4 * 4 + 2][row] = v.z; Vt[c4 * 4 + 3][row] = v.w;
    }
    float m = redm[qq][0];
#pragma unroll
    for (int t = 1; t < 8; ++t) m = fmaxf(m, redm[qq][t]);
    float psum = 0.f;
#pragma unroll
    for (int kk = 0; kk < 8; ++kk) {
        float e = expf(sc[kk] - m);
        Pl[qq][k0 + kk] = e;
        psum += e;
    }
    redl[qq][g] = psum;
    __syncthreads();
    float lsum = redl[qq][0];
#pragma unroll
    for (int t = 1; t < 8; ++t) lsum += redl[qq][t];
    float o[8] = {};
    for (int k4 = 0; k4 < 16; ++k4) {
        float4 p4 = *(const float4*)&Pl[qq][k4 * 4];
        float pv[4] = {p4.x, p4.y, p4.z, p4.w};
#pragma unroll
        for (int dd = 0; dd < 8; ++dd) {
            float4 v4 = *(const float4*)&Vt[k0 + dd][k4 * 4];
            o[dd] += pv[0] * v4.x + pv[1] * v4.y + pv[2] * v4.z + pv[3] * v4.w;
        }
    }
    float* dst = PV + (((size_t)pair * LQ + s) << 6) + k0;
    float4 o0, o1;
    o0.x = o[0]; o0.y = o[1]; o0.z = o[2]; o0.w = o[3];
    o1.x = o[4]; o1.y = o[5]; o1.z = o[6]; o1.w = o[7];
    *(float4*)dst = o0; *(float4*)(dst + 4) = o1;
    if (g == 0) ML[(size_t)pair * LQ + s] = make_float2(m, lsum);
}

// ---------------- K5: output projection (32x64 tiles, fp16) with fused combine ----------------
__global__ __launch_bounds__(256) void out_combine(const float* __restrict__ PV,
                                                   const float2* __restrict__ ML,
                                                   const int* __restrict__ OIDX,
                                                   const ushort_t* __restrict__ WoTh,
                                                   const float* __restrict__ bo,
                                                   float* __restrict__ out) {
    __shared__ __align__(16) char SM[6144];    // Ah@0(2KB) Bh@2048(4KB)
    const int tid = threadIdx.x;
    const int b = blockIdx.x;
    const int m0 = (b >> 3) * 32, n0 = (b & 7) * 64;
    const int wave = tid >> 6, lane = tid & 63;
    const int wm_ = wave & 1, wn_ = wave >> 1;
    const int arow = tid >> 3;
    const int abyte = arow * 64 + ((((tid & 7) >> 1) ^ (arow & 3)) << 4) + (tid & 1) * 8;
    const int brow = tid >> 2, bs = tid & 3;
    const int bbyte = brow * 64 + ((bs ^ (brow & 3)) << 4);
    const size_t gB = (size_t)(n0 + brow) * DD + bs * 8;
    const int kb = lane >> 4;
    const int far_ = wm_ * 16 + (lane & 15);
    const int fabyte = far_ * 64 + ((kb ^ (far_ & 3)) << 4);
    int fbbyte[2];
#pragma unroll
    for (int j = 0; j < 2; ++j) {
        int c = wn_ * 32 + j * 16 + (lane & 15);
        fbbyte[j] = c * 64 + ((kb ^ (c & 3)) << 4);
    }
    const int l = m0 + arow;
    float4 a0, a1; float2 ml0, ml1;
    {
        int head = 0;
        int d0 = (tid & 7) * 4;
        size_t p0 = (size_t)head * RR, p1 = p0 + 1;
        int s0 = OIDX[p0 * LQ + l], s1 = OIDX[p1 * LQ + l];
        ml0 = ML[p0 * LQ + s0]; ml1 = ML[p1 * LQ + s1];
        a0 = *(const float4*)(PV + ((p0 * LQ + s0) << 6) + d0);
        a1 = *(const float4*)(PV + ((p1 * LQ + s1) << 6) + d0);
    }
    uint4 whx = *(const uint4*)(WoTh + gB);
    f32x4 acc[2] = {};
    for (int kt = 0; kt < DD; kt += 32) {
        __syncthreads();
        {
            float M = fmaxf(ml0.x, ml1.x);
            float w0 = expf(ml0.x - M);
            float w1 = expf(ml1.x - M);
            float denom = w0 * ml0.y + w1 * ml1.y;
            float av0[4] = {a0.x, a0.y, a0.z, a0.w};
            float av1[4] = {a1.x, a1.y, a1.z, a1.w};
            ushort_t h4[4];
#pragma unroll
            for (int i = 0; i < 4; ++i)
                h4[i] = f16b((w0 * av0[i] + w1 * av1[i]) / denom);
            store4u((ushort_t*)(SM + abyte), h4);
            *(uint4*)(SM + 2048 + bbyte) = whx;
        }
        __syncthreads();
        if (kt + 32 < DD) {
            int ktn = kt + 32;
            int head = ktn >> 6;
            int d0 = (ktn & 63) + (tid & 7) * 4;
            size_t p0 = (size_t)head * RR, p1 = p0 + 1;
            int s0 = OIDX[p0 * LQ + l], s1 = OIDX[p1 * LQ + l];
            ml0 = ML[p0 * LQ + s0]; ml1 = ML[p1 * LQ + s1];
            a0 = *(const float4*)(PV + ((p0 * LQ + s0) << 6) + d0);
            a1 = *(const float4*)(PV + ((p1 * LQ + s1) << 6) + d0);
            whx = *(const uint4*)(WoTh + gB + ktn);
        }
        f16x8 ah = *(const f16x8*)(SM + fabyte);
        f16x8 bh0 = *(const f16x8*)(SM + 2048 + fbbyte[0]);
        f16x8 bh1 = *(const f16x8*)(SM + 2048 + fbbyte[1]);
        acc[0] = __builtin_amdgcn_mfma_f32_16x16x32_f16(ah, bh0, acc[0], 0, 0, 0);
        acc[1] = __builtin_amdgcn_mfma_f32_16x16x32_f16(ah, bh1, acc[1], 0, 0, 0);
    }
#pragma unroll
    for (int j = 0; j < 2; ++j) {
        int cl = wn_ * 32 + j * 16 + (lane & 15);
        float bb_ = bo[n0 + cl];
#pragma unroll
        for (int reg = 0; reg < 4; ++reg) {
            int rl = wm_ * 16 + (lane >> 4) * 4 + reg;
            out[(size_t)(m0 + rl) * DD + n0 + cl] = acc[j][reg] + bb_;
        }
    }
}

extern "C" void kernel_launch(void* const* d_in, const int* in_sizes, int n_in,
                              void* d_out, int out_size, void* d_ws, size_t ws_size,
                              hipStream_t stream) {
    const float* query = (const float*)d_in[0];
    const float* value = (const float*)d_in[2];
    const float* Wq = (const float*)d_in[4];
    const float* bq = (const float*)d_in[5];
    const float* Wv = (const float*)d_in[6];
    const float* bv = (const float*)d_in[7];
    const float* Wo = (const float*)d_in[8];
    const float* bo = (const float*)d_in[9];
    const float* rnd = (const float*)d_in[10];

    char* ws = (char*)d_ws;
    const size_t MB1 = 1u << 20;
    const size_t HK = 512u << 10;
    float*    Qf    = (float*)(ws);                       // [0,2MB)
    float*    Vf    = (float*)(ws + 2 * MB1);             // [2,4MB)
    float*    P0    = (float*)(ws + 4 * MB1);             // [4,6MB)  dead after hash
    float*    P1    = (float*)(ws + 6 * MB1);             // [6,8MB)  dead after hash
    float*    PV    = (float*)(ws + 4 * MB1);             // [4,8MB)  overlays P0/P1 (spv after hash)
    ushort_t* WqTh  = (ushort_t*)(ws + 8 * MB1);          // [8.0,8.5)
    ushort_t* WqTm  = (ushort_t*)(ws + 8 * MB1 + HK);     // [8.5,9.0)
    ushort_t* WvTh  = (ushort_t*)(ws + 9 * MB1);          // [9.0,9.5)
    ushort_t* WoTh  = (ushort_t*)(ws + 9 * MB1 + HK);     // [9.5,10.0)
    float*    RNORM = (float*)(ws + 10 * MB1);            // 32KB
    char*     tail  = ws + 10 * MB1 + (64u << 10);
    int* HASH  = (int*)(tail);
    int* HIDX  = (int*)(tail + (64u << 10));
    int* OIDX  = (int*)(tail + (128u << 10));
    int* HSORT = (int*)(tail + (192u << 10));
    float2* ML = (float2*)(tail + (256u << 10));          // 128KB
    float* OUT = (float*)d_out;

    prep_w<<<768, 256, 0, stream>>>(Wq, Wv, Wo, WqTh, WqTm, WvTh, WoTh);
    gemm_all<<<768, 256, 0, stream>>>(query, value, WqTh, WqTm, WvTh, bv, P0, P1, Vf);
    hash_kernel<<<256, 256, 0, stream>>>(P0, P1, bq, rnd, Qf, HASH, RNORM);
    sort_kernel<<<16, 256, 0, stream>>>(HASH, HIDX, OIDX, HSORT);
    spv_kernel<<<dim3(32, 2, 8), 256, 0, stream>>>(Qf, RNORM, Vf, HIDX, OIDX, HSORT, PV, ML);
    out_combine<<<256, 256, 0, stream>>>(PV, ML, OIDX, WoTh, bo, OUT);
}

// Round 9
// 77.220 us; speedup vs baseline: 5.5258x; 1.1095x over previous
//
#include <hip/hip_runtime.h>
#include <math.h>

#define LQ 1024
#define DD 512
#define DK 64
#define RR 2

typedef unsigned short ushort_t;
typedef __attribute__((ext_vector_type(8))) _Float16 f16x8;
typedef __attribute__((ext_vector_type(4))) float f32x4;

__device__ inline ushort_t f16b(float x) {
    union { _Float16 h; ushort_t u; } c; c.h = (_Float16)x; return c.u;
}
__device__ inline float f16tof(ushort_t u) {
    union { ushort_t u; _Float16 h; } c; c.u = u; return (float)c.h;
}
__device__ inline void store4u(ushort_t* p, const ushort_t h[4]) {
    uint2 v;
    v.x = h[0] | ((unsigned int)h[1] << 16); v.y = h[2] | ((unsigned int)h[3] << 16);
    *(uint2*)p = v;
}

// ---------------- K0: weight transposes (Wq 2-level fp16, Wv/Wo 1-level fp16) ----------------
__global__ __launch_bounds__(256) void prep_w(const float* __restrict__ Wq,
                                              const float* __restrict__ Wv,
                                              const float* __restrict__ Wo,
                                              ushort_t* __restrict__ WqTh, ushort_t* __restrict__ WqTm,
                                              ushort_t* __restrict__ WvTh, ushort_t* __restrict__ WoTh) {
    __shared__ float tl[32][33];
    const int tid = threadIdx.x;
    const int b = blockIdx.x;
    const int mat = b >> 8;                // 0 Wq, 1 Wv, 2 Wo
    const int tile = b & 255;
    const int r0 = (tile >> 4) * 32;       // k rows
    const int c0 = (tile & 15) * 32;       // n cols
    const float* W = (mat == 0) ? Wq : ((mat == 1) ? Wv : Wo);
    const int rr = tid >> 3, cc = (tid & 7) * 4;
    *(float4*)&tl[rr][cc] = *(const float4*)(W + (size_t)(r0 + rr) * DD + c0 + cc);
    __syncthreads();
    float y[4];
#pragma unroll
    for (int i = 0; i < 4; ++i) y[i] = tl[cc + i][rr];
    size_t ob = (size_t)(c0 + rr) * DD + r0 + cc;
    if (mat == 0) {
        ushort_t h[4], m[4];
#pragma unroll
        for (int i = 0; i < 4; ++i) {
            h[i] = f16b(y[i]);
            m[i] = f16b((y[i] - f16tof(h[i])) * 2048.f);
        }
        store4u(WqTh + ob, h); store4u(WqTm + ob, m);
    } else {
        ushort_t h[4];
#pragma unroll
        for (int i = 0; i < 4; ++i) h[i] = f16b(y[i]);
        store4u((mat == 1 ? WvTh : WoTh) + ob, h);
    }
}

// ---------------- K1: projections + fused hash ----------------
// blocks [0,256): Q both fp16-split passes (acc0=hh, acc1=hm+mh) + fused hash epilogue
// blocks [256,512): V single pass (+bias)
__global__ __launch_bounds__(256) void gemm_hash(const float* __restrict__ query,
                                                 const float* __restrict__ value,
                                                 const ushort_t* __restrict__ WqTh,
                                                 const ushort_t* __restrict__ WqTm,
                                                 const ushort_t* __restrict__ WvTh,
                                                 const float* __restrict__ bq,
                                                 const float* __restrict__ bv,
                                                 const float* __restrict__ rnd,
                                                 float* __restrict__ Qf, float* __restrict__ Vf,
                                                 int* __restrict__ HASH, float* __restrict__ RNORM) {
    __shared__ __align__(16) char SM[24704];   // gemm: Ah@0 Am@2048 Bh@4096 Bm@8192 | epi: qtile@0(8320) rmn@8320(16384)
    const int tid = threadIdx.x;
    const int b = blockIdx.x;
    const bool isQ = (b < 256);
    const int t = isQ ? b : b - 256;
    const int m0 = (t >> 3) * 32, n0 = (t & 7) * 64;
    const int wave = tid >> 6, lane = tid & 63;
    const int wm_ = wave & 1, wn_ = wave >> 1;
    // staging coords
    const int arow = tid >> 3;
    const int abyte = arow * 64 + ((((tid & 7) >> 1) ^ (arow & 3)) << 4) + (tid & 1) * 8;
    const int brow = tid >> 2, bs = tid & 3;
    const int bbyte = brow * 64 + ((bs ^ (brow & 3)) << 4);
    const size_t gA = (size_t)(m0 + arow) * DD + (tid & 7) * 4;
    const size_t gB = (size_t)(n0 + brow) * DD + bs * 8;
    // fragment offsets
    const int kb = lane >> 4;
    const int far_ = wm_ * 16 + (lane & 15);
    const int fabyte = far_ * 64 + ((kb ^ (far_ & 3)) << 4);
    int fbbyte[2];
#pragma unroll
    for (int j = 0; j < 2; ++j) {
        int c = wn_ * 32 + j * 16 + (lane & 15);
        fbbyte[j] = c * 64 + ((kb ^ (c & 3)) << 4);
    }
    const float* Asrc = isQ ? query : value;
    const ushort_t* Bh_src = isQ ? WqTh : WvTh;
    f32x4 acc0[2] = {};
    f32x4 acc1[2] = {};
    float4 xa = *(const float4*)(Asrc + gA);
    uint4 wh = *(const uint4*)(Bh_src + gB);
    uint4 wm = {};
    if (isQ) wm = *(const uint4*)(WqTm + gB);
    for (int kt = 0; kt < DD; kt += 32) {
        __syncthreads();
        {
            float xs[4] = {xa.x, xa.y, xa.z, xa.w};
            ushort_t h4[4];
#pragma unroll
            for (int i = 0; i < 4; ++i) h4[i] = f16b(xs[i]);
            store4u((ushort_t*)(SM + abyte), h4);
            if (isQ) {
                ushort_t m4[4];
#pragma unroll
                for (int i = 0; i < 4; ++i)
                    m4[i] = f16b((xs[i] - f16tof(h4[i])) * 2048.f);
                store4u((ushort_t*)(SM + 2048 + abyte), m4);
            }
            *(uint4*)(SM + 4096 + bbyte) = wh;
            if (isQ) *(uint4*)(SM + 8192 + bbyte) = wm;
        }
        __syncthreads();
        if (kt + 32 < DD) {                      // issue-early prefetch (overlaps MFMA below)
            xa = *(const float4*)(Asrc + gA + kt + 32);
            wh = *(const uint4*)(Bh_src + gB + kt + 32);
            if (isQ) wm = *(const uint4*)(WqTm + gB + kt + 32);
        }
        f16x8 ah = *(const f16x8*)(SM + fabyte);
        f16x8 bh0 = *(const f16x8*)(SM + 4096 + fbbyte[0]);
        f16x8 bh1 = *(const f16x8*)(SM + 4096 + fbbyte[1]);
        // pass-0 order (hh), identical to round-8 pass 0
        acc0[0] = __builtin_amdgcn_mfma_f32_16x16x32_f16(ah, bh0, acc0[0], 0, 0, 0);
        acc0[1] = __builtin_amdgcn_mfma_f32_16x16x32_f16(ah, bh1, acc0[1], 0, 0, 0);
        if (isQ) {
            f16x8 am = *(const f16x8*)(SM + 2048 + fabyte);
            f16x8 bm0 = *(const f16x8*)(SM + 8192 + fbbyte[0]);
            f16x8 bm1 = *(const f16x8*)(SM + 8192 + fbbyte[1]);
            // pass-1 order (hm+mh), identical to round-8 pass 1
            acc1[0] = __builtin_amdgcn_mfma_f32_16x16x32_f16(ah, bm0, acc1[0], 0, 0, 0);
            acc1[0] = __builtin_amdgcn_mfma_f32_16x16x32_f16(am, bh0, acc1[0], 0, 0, 0);
            acc1[1] = __builtin_amdgcn_mfma_f32_16x16x32_f16(ah, bm1, acc1[1], 0, 0, 0);
            acc1[1] = __builtin_amdgcn_mfma_f32_16x16x32_f16(am, bh1, acc1[1], 0, 0, 0);
        }
    }
    __syncthreads();                             // all fragment reads done; LDS reusable
    if (!isQ) {
#pragma unroll
        for (int j = 0; j < 2; ++j) {
            int cl = wn_ * 32 + j * 16 + (lane & 15);
            float bias_ = bv[n0 + cl];
#pragma unroll
            for (int reg = 0; reg < 4; ++reg) {
                int rl = wm_ * 16 + (lane >> 4) * 4 + reg;
                Vf[(size_t)n0 * LQ + (size_t)(m0 + rl) * DK + cl] = acc0[j][reg] + bias_;
            }
        }
        return;
    }
    // ---- Q epilogue: combine passes (bit-identical to round-8 hash input), store, fused hash ----
    float (*qtile)[65] = (float(*)[65])SM;       // 8320 B
    float (*rmn)[64] = (float(*)[64])(SM + 8320);
#pragma unroll
    for (int j = 0; j < 2; ++j) {
        int cl = wn_ * 32 + j * 16 + (lane & 15);
        float bq_ = bq[n0 + cl];
#pragma unroll
        for (int reg = 0; reg < 4; ++reg) {
            int rl = wm_ * 16 + (lane >> 4) * 4 + reg;
            float x = acc0[j][reg] + acc1[j][reg] * (1.f / 2048.f) + bq_;
            Qf[(size_t)n0 * LQ + (size_t)(m0 + rl) * DK + cl] = x;
            qtile[rl][cl] = x;
        }
    }
    for (int idx = tid; idx < 4096; idx += 256)
        rmn[idx >> 6][idx & 63] = rnd[idx];
    __syncthreads();
    if (tid < 128) {
        int d = tid >> 1, rh = tid & 1;
        float s = 0.f;
        for (int j = 0; j < 32; ++j) { float x = rmn[d][rh * 32 + j]; s += x * x; }
        float nrm = sqrtf(s);
        for (int j = 0; j < 32; ++j) rmn[d][rh * 32 + j] = rmn[d][rh * 32 + j] / nrm;
    }
    __syncthreads();
    const int j = lane & 31, r = lane >> 5;
    const int bh = n0 >> 6;
    for (int it = 0; it < 8; ++it) {
        const int rl = it * 4 + wave;
        const int row = (bh << 10) + m0 + rl;    // bh*1024 + l
        float x = qtile[rl][lane];
        float s2 = x * x;
#pragma unroll
        for (int m = 1; m < 64; m <<= 1) s2 += __shfl_xor(s2, m);
        if (lane == 0) RNORM[row] = 1.0f / sqrtf(s2);
        float p0 = 0.f, p1 = 0.f, p2 = 0.f, p3 = 0.f;
#pragma unroll 4
        for (int d = 0; d < 64; d += 4) {
            p0 += __shfl(x, d + 0) * rmn[d + 0][lane];
            p1 += __shfl(x, d + 1) * rmn[d + 1][lane];
            p2 += __shfl(x, d + 2) * rmn[d + 2][lane];
            p3 += __shfl(x, d + 3) * rmn[d + 3][lane];
        }
        float p = (p0 + p1) + (p2 + p3);
        float bv_; int bi;
        if (p >= -p) { bv_ = p; bi = j; } else { bv_ = -p; bi = 32 + j; }
#pragma unroll
        for (int m = 1; m < 32; m <<= 1) {
            float ov = __shfl_xor(bv_, m);
            int oi = __shfl_xor(bi, m);
            if (ov > bv_ || (ov == bv_ && oi < bi)) { bv_ = ov; bi = oi; }
        }
        if (j == 0) HASH[((size_t)bh * RR + r) * LQ + m0 + rl] = bi;
    }
}

// ---------------- K2: stable counting sort per (bh, r) ----------------
__global__ __launch_bounds__(256) void sort_kernel(const int* __restrict__ HASH,
                                                   int* __restrict__ HIDX,
                                                   int* __restrict__ OIDX,
                                                   int* __restrict__ HSORT) {
    __shared__ __align__(16) char SM[39424];
    int* hl = (int*)SM;
    ushort_t (*cnt)[64] = (ushort_t(*)[64])(SM + 4096);
    int (*psum)[4] = (int(*)[4])(SM + 36864);
    int (*poff)[4] = (int(*)[4])(SM + 37888);
    int* base = (int*)(SM + 38912);
    const int tid = threadIdx.x;
    const int pair = blockIdx.x;
    const int* hsrc = HASH + (size_t)pair * LQ;
    for (int i = tid; i < 1024; i += 256) hl[i] = hsrc[i];
    int* cz = (int*)(SM + 4096);
    for (int i = tid; i < 8192; i += 256) cz[i] = 0;
    __syncthreads();
    for (int i = 0; i < 4; ++i) {
        int h = hl[tid * 4 + i];
        cnt[tid][h] += 1;
    }
    __syncthreads();
    {
        int h = tid >> 2, seg = tid & 3;
        int run = 0;
        for (int tt = seg * 64; tt < seg * 64 + 64; ++tt) {
            int tmp = cnt[tt][h];
            cnt[tt][h] = (ushort_t)run;
            run += tmp;
        }
        psum[h][seg] = run;
    }
    __syncthreads();
    if (tid < 64) {
        int run = 0;
#pragma unroll
        for (int seg = 0; seg < 4; ++seg) { int t = psum[tid][seg]; poff[tid][seg] = run; run += t; }
        int incl = run;
#pragma unroll
        for (int d = 1; d < 64; d <<= 1) {
            int y = __shfl_up(incl, d);
            if (tid >= d) incl += y;
        }
        base[tid] = incl - run;
    }
    __syncthreads();
    int* HI = HIDX + (size_t)pair * LQ;
    int* OI = OIDX + (size_t)pair * LQ;
    int* HS = HSORT + (size_t)pair * LQ;
    const int myseg = tid >> 6;
    for (int i = 0; i < 4; ++i) {
        int l = tid * 4 + i;
        int h = hl[l];
        int pos = base[h] + poff[h][myseg] + cnt[tid][h];
        cnt[tid][h] = (ushort_t)(cnt[tid][h] + 1);
        HI[pos] = l;
        OI[l] = pos;
        HS[pos] = h;
    }
}

// ---------------- K3: fused scores + per-pair softmax partials + PV ----------------
__global__ __launch_bounds__(256) void spv_kernel(const float* __restrict__ Q,
                                                  const float* __restrict__ RNORM,
                                                  const float* __restrict__ Vf,
                                                  const int* __restrict__ HIDX,
                                                  const int* __restrict__ OIDX,
                                                  const int* __restrict__ HSORT,
                                                  float* __restrict__ PV,
                                                  float2* __restrict__ ML) {
    const int n = blockIdx.x, r = blockIdx.y, bh = blockIdx.z;
    const int pair = bh * RR + r;
    __shared__ __align__(16) char SM[37440];
    float (*Qs)[65] = (float(*)[65])SM;
    float (*Ks)[65] = (float(*)[65])(SM + 8320);
    float (*Vt)[68] = (float(*)[68])SM;
    float (*Pl)[68] = (float(*)[68])(SM + 25024);
    float (*redm)[8] = (float(*)[8])(SM + 33728);
    float (*redl)[8] = (float(*)[8])(SM + 34752);
    int* qi_l = (int*)(SM + 35776);
    int* hsq  = (int*)(SM + 35904);
    int* Aq   = (int*)(SM + 36032);
    int* ki_l = (int*)(SM + 36160);
    int* hsk  = (int*)(SM + 36416);
    int* Ak   = (int*)(SM + 36672);
    float* krn  = (float*)(SM + 36928);
    float* lcnt = (float*)(SM + 37184);
    const int tid = threadIdx.x;
    const int* HI = HIDX + (size_t)pair * LQ;
    const int* OI = OIDX + (size_t)pair * LQ;
    const int* HS = HSORT + (size_t)pair * LQ;
    if (tid < 32) {
        int s = n * 32 + tid;
        qi_l[tid] = HI[s]; hsq[tid] = HS[s]; Aq[tid] = OI[s];
    } else if (tid < 96) {
        int k = tid - 32;
        int t = (n - 1) * 32 + k;
        if (t < 0) { ki_l[k] = -1; hsk[k] = 0; Ak[k] = 0; krn[k] = 0.f; }
        else {
            int ki = HI[t];
            ki_l[k] = ki; hsk[k] = HS[t]; Ak[k] = OI[t];
            krn[k] = RNORM[(size_t)bh * LQ + ki];
        }
    }
    __syncthreads();
    if (tid == 0) {
        if (n > 0) {
            for (int k = 0; k < 64; ++k) lcnt[k] = 0.f;
        } else {
            int zc = 0;
            for (int k = 32; k < 64; ++k) zc += (Ak[k] == 0);
            float l32 = logf((float)(32 + zc));
            for (int k = 0; k < 32; ++k) lcnt[k] = l32;
            for (int k = 32; k < 64; ++k) lcnt[k] = (Ak[k] == 0) ? l32 : 0.f;
        }
    }
    for (int idx = tid; idx < 32 * 16; idx += 256) {
        int row = idx >> 4, c4 = idx & 15;
        float4 v = ((const float4*)(Q + ((size_t)bh * LQ + qi_l[row]) * DK))[c4];
        Qs[row][c4 * 4 + 0] = v.x; Qs[row][c4 * 4 + 1] = v.y;
        Qs[row][c4 * 4 + 2] = v.z; Qs[row][c4 * 4 + 3] = v.w;
    }
    for (int idx = tid; idx < 64 * 16; idx += 256) {
        int row = idx >> 4, c4 = idx & 15;
        int ki = ki_l[row];
        float4 v;
        if (ki < 0) { v.x = 0.f; v.y = 0.f; v.z = 0.f; v.w = 0.f; }
        else {
            v = ((const float4*)(Q + ((size_t)bh * LQ + ki) * DK))[c4];
            float rn = krn[row];
            v.x *= rn; v.y *= rn; v.z *= rn; v.w *= rn;
        }
        Ks[row][c4 * 4 + 0] = v.x; Ks[row][c4 * 4 + 1] = v.y;
        Ks[row][c4 * 4 + 2] = v.z; Ks[row][c4 * 4 + 3] = v.w;
    }
    __syncthreads();
    const int qq = tid & 31;
    const int g = tid >> 5;
    const int k0 = g * 8;
    float acc[8] = {};
    for (int d = 0; d < 64; ++d) {
        float qv = Qs[qq][d];
#pragma unroll
        for (int kk = 0; kk < 8; ++kk) acc[kk] += qv * Ks[k0 + kk][d];
    }
    const int s = n * 32 + qq;
    const int aq = Aq[qq], hq = hsq[qq];
    float sc[8];
    float pm = -3.4e38f;
#pragma unroll
    for (int kk = 0; kk < 8; ++kk) {
        int k = k0 + kk;
        float v = acc[kk] * 0.125f;
        v = v - ((n == 0 && k < 32) ? 1e9f : 0.f);
        v = v - ((hq == hsk[k]) ? 0.f : 1e9f);
        v = v - ((aq > Ak[k]) ? 0.f : 1e9f);
        v = v - ((aq == Ak[k]) ? 1e5f : 0.f);
        v = v - lcnt[k];
        sc[kk] = v;
        pm = fmaxf(pm, v);
    }
    redm[qq][g] = pm;
    __syncthreads();
    for (int idx = tid; idx < 64 * 16; idx += 256) {
        int row = idx >> 4, c4 = idx & 15;
        int ki = ki_l[row];
        float4 v;
        if (ki < 0) { v.x = 0.f; v.y = 0.f; v.z = 0.f; v.w = 0.f; }
        else v = ((const float4*)(Vf + ((size_t)bh * LQ + ki) * DK))[c4];
        Vt[c4 * 4 + 0][row] = v.x; Vt[c4 * 4 + 1][row] = v.y;
        Vt[c4 * 4 + 2][row] = v.z; Vt[c4 * 4 + 3][row] = v.w;
    }
    float m = redm[qq][0];
#pragma unroll
    for (int t = 1; t < 8; ++t) m = fmaxf(m, redm[qq][t]);
    float psum = 0.f;
#pragma unroll
    for (int kk = 0; kk < 8; ++kk) {
        float e = expf(sc[kk] - m);
        Pl[qq][k0 + kk] = e;
        psum += e;
    }
    redl[qq][g] = psum;
    __syncthreads();
    float lsum = redl[qq][0];
#pragma unroll
    for (int t = 1; t < 8; ++t) lsum += redl[qq][t];
    float o[8] = {};
    for (int k4 = 0; k4 < 16; ++k4) {
        float4 p4 = *(const float4*)&Pl[qq][k4 * 4];
        float pv[4] = {p4.x, p4.y, p4.z, p4.w};
#pragma unroll
        for (int dd = 0; dd < 8; ++dd) {
            float4 v4 = *(const float4*)&Vt[k0 + dd][k4 * 4];
            o[dd] += pv[0] * v4.x + pv[1] * v4.y + pv[2] * v4.z + pv[3] * v4.w;
        }
    }
    float* dst = PV + (((size_t)pair * LQ + s) << 6) + k0;
    float4 o0, o1;
    o0.x = o[0]; o0.y = o[1]; o0.z = o[2]; o0.w = o[3];
    o1.x = o[4]; o1.y = o[5]; o1.z = o[6]; o1.w = o[7];
    *(float4*)dst = o0; *(float4*)(dst + 4) = o1;
    if (g == 0) ML[(size_t)pair * LQ + s] = make_float2(m, lsum);
}

// ---------------- K4: output projection (32x64 tiles, fp16) with fused combine ----------------
__global__ __launch_bounds__(256) void out_combine(const float* __restrict__ PV,
                                                   const float2* __restrict__ ML,
                                                   const int* __restrict__ OIDX,
                                                   const ushort_t* __restrict__ WoTh,
                                                   const float* __restrict__ bo,
                                                   float* __restrict__ out) {
    __shared__ __align__(16) char SM[6144];    // Ah@0(2KB) Bh@2048(4KB)
    const int tid = threadIdx.x;
    const int b = blockIdx.x;
    const int m0 = (b >> 3) * 32, n0 = (b & 7) * 64;
    const int wave = tid >> 6, lane = tid & 63;
    const int wm_ = wave & 1, wn_ = wave >> 1;
    const int arow = tid >> 3;
    const int abyte = arow * 64 + ((((tid & 7) >> 1) ^ (arow & 3)) << 4) + (tid & 1) * 8;
    const int brow = tid >> 2, bs = tid & 3;
    const int bbyte = brow * 64 + ((bs ^ (brow & 3)) << 4);
    const size_t gB = (size_t)(n0 + brow) * DD + bs * 8;
    const int kb = lane >> 4;
    const int far_ = wm_ * 16 + (lane & 15);
    const int fabyte = far_ * 64 + ((kb ^ (far_ & 3)) << 4);
    int fbbyte[2];
#pragma unroll
    for (int j = 0; j < 2; ++j) {
        int c = wn_ * 32 + j * 16 + (lane & 15);
        fbbyte[j] = c * 64 + ((kb ^ (c & 3)) << 4);
    }
    const int l = m0 + arow;
    float4 a0, a1; float2 ml0, ml1;
    {
        int head = 0;
        int d0 = (tid & 7) * 4;
        size_t p0 = (size_t)head * RR, p1 = p0 + 1;
        int s0 = OIDX[p0 * LQ + l], s1 = OIDX[p1 * LQ + l];
        ml0 = ML[p0 * LQ + s0]; ml1 = ML[p1 * LQ + s1];
        a0 = *(const float4*)(PV + ((p0 * LQ + s0) << 6) + d0);
        a1 = *(const float4*)(PV + ((p1 * LQ + s1) << 6) + d0);
    }
    uint4 whx = *(const uint4*)(WoTh + gB);
    f32x4 acc[2] = {};
    for (int kt = 0; kt < DD; kt += 32) {
        __syncthreads();
        {
            float M = fmaxf(ml0.x, ml1.x);
            float w0 = expf(ml0.x - M);
            float w1 = expf(ml1.x - M);
            float denom = w0 * ml0.y + w1 * ml1.y;
            float av0[4] = {a0.x, a0.y, a0.z, a0.w};
            float av1[4] = {a1.x, a1.y, a1.z, a1.w};
            ushort_t h4[4];
#pragma unroll
            for (int i = 0; i < 4; ++i)
                h4[i] = f16b((w0 * av0[i] + w1 * av1[i]) / denom);
            store4u((ushort_t*)(SM + abyte), h4);
            *(uint4*)(SM + 2048 + bbyte) = whx;
        }
        __syncthreads();
        if (kt + 32 < DD) {
            int ktn = kt + 32;
            int head = ktn >> 6;
            int d0 = (ktn & 63) + (tid & 7) * 4;
            size_t p0 = (size_t)head * RR, p1 = p0 + 1;
            int s0 = OIDX[p0 * LQ + l], s1 = OIDX[p1 * LQ + l];
            ml0 = ML[p0 * LQ + s0]; ml1 = ML[p1 * LQ + s1];
            a0 = *(const float4*)(PV + ((p0 * LQ + s0) << 6) + d0);
            a1 = *(const float4*)(PV + ((p1 * LQ + s1) << 6) + d0);
            whx = *(const uint4*)(WoTh + gB + ktn);
        }
        f16x8 ah = *(const f16x8*)(SM + fabyte);
        f16x8 bh0 = *(const f16x8*)(SM + 2048 + fbbyte[0]);
        f16x8 bh1 = *(const f16x8*)(SM + 2048 + fbbyte[1]);
        acc[0] = __builtin_amdgcn_mfma_f32_16x16x32_f16(ah, bh0, acc[0], 0, 0, 0);
        acc[1] = __builtin_amdgcn_mfma_f32_16x16x32_f16(ah, bh1, acc[1], 0, 0, 0);
    }
#pragma unroll
    for (int j = 0; j < 2; ++j) {
        int cl = wn_ * 32 + j * 16 + (lane & 15);
        float bb_ = bo[n0 + cl];
#pragma unroll
        for (int reg = 0; reg < 4; ++reg) {
            int rl = wm_ * 16 + (lane >> 4) * 4 + reg;
            out[(size_t)(m0 + rl) * DD + n0 + cl] = acc[j][reg] + bb_;
        }
    }
}

extern "C" void kernel_launch(void* const* d_in, const int* in_sizes, int n_in,
                              void* d_out, int out_size, void* d_ws, size_t ws_size,
                              hipStream_t stream) {
    const float* query = (const float*)d_in[0];
    const float* value = (const float*)d_in[2];
    const float* Wq = (const float*)d_in[4];
    const float* bq = (const float*)d_in[5];
    const float* Wv = (const float*)d_in[6];
    const float* bv = (const float*)d_in[7];
    const float* Wo = (const float*)d_in[8];
    const float* bo = (const float*)d_in[9];
    const float* rnd = (const float*)d_in[10];

    char* ws = (char*)d_ws;
    const size_t MB1 = 1u << 20;
    const size_t HK = 512u << 10;
    float*    Qf    = (float*)(ws);                       // [0,2MB)
    float*    Vf    = (float*)(ws + 2 * MB1);             // [2,4MB)
    float*    PV    = (float*)(ws + 4 * MB1);             // [4,8MB)
    ushort_t* WqTh  = (ushort_t*)(ws + 8 * MB1);          // [8.0,8.5)
    ushort_t* WqTm  = (ushort_t*)(ws + 8 * MB1 + HK);     // [8.5,9.0)
    ushort_t* WvTh  = (ushort_t*)(ws + 9 * MB1);          // [9.0,9.5)
    ushort_t* WoTh  = (ushort_t*)(ws + 9 * MB1 + HK);     // [9.5,10.0)
    float*    RNORM = (float*)(ws + 10 * MB1);            // 32KB
    char*     tail  = ws + 10 * MB1 + (64u << 10);
    int* HASH  = (int*)(tail);
    int* HIDX  = (int*)(tail + (64u << 10));
    int* OIDX  = (int*)(tail + (128u << 10));
    int* HSORT = (int*)(tail + (192u << 10));
    float2* ML = (float2*)(tail + (256u << 10));          // 128KB
    float* OUT = (float*)d_out;

    prep_w<<<768, 256, 0, stream>>>(Wq, Wv, Wo, WqTh, WqTm, WvTh, WoTh);
    gemm_hash<<<512, 256, 0, stream>>>(query, value, WqTh, WqTm, WvTh, bq, bv, rnd,
                                       Qf, Vf, HASH, RNORM);
    sort_kernel<<<16, 256, 0, stream>>>(HASH, HIDX, OIDX, HSORT);
    spv_kernel<<<dim3(32, 2, 8), 256, 0, stream>>>(Qf, RNORM, Vf, HIDX, OIDX, HSORT, PV, ML);
    out_combine<<<256, 256, 0, stream>>>(PV, ML, OIDX, WoTh, bo, OUT);
}

// Round 10
// 71.052 us; speedup vs baseline: 6.0055x; 1.0868x over previous
//
#include <hip/hip_runtime.h>
#include <math.h>

#define LQ 1024
#define DD 512
#define DK 64
#define RR 2

typedef unsigned short ushort_t;
typedef __attribute__((ext_vector_type(8))) _Float16 f16x8;
typedef __attribute__((ext_vector_type(4))) float f32x4;

__device__ inline ushort_t f16b(float x) {
    union { _Float16 h; ushort_t u; } c; c.h = (_Float16)x; return c.u;
}
__device__ inline float f16tof(ushort_t u) {
    union { ushort_t u; _Float16 h; } c; c.u = u; return (float)c.h;
}
__device__ inline void store4u(ushort_t* p, const ushort_t h[4]) {
    uint2 v;
    v.x = h[0] | ((unsigned int)h[1] << 16); v.y = h[2] | ((unsigned int)h[3] << 16);
    *(uint2*)p = v;
}
__device__ inline uint4 pku(float4 a, float4 b) {
    uint4 v;
    v.x = (unsigned)f16b(a.x) | ((unsigned)f16b(a.y) << 16);
    v.y = (unsigned)f16b(a.z) | ((unsigned)f16b(a.w) << 16);
    v.z = (unsigned)f16b(b.x) | ((unsigned)f16b(b.y) << 16);
    v.w = (unsigned)f16b(b.z) | ((unsigned)f16b(b.w) << 16);
    return v;
}
__device__ inline f16x8 pk8(float4 a, float4 b) {
    f16x8 r;
    r[0] = (_Float16)a.x; r[1] = (_Float16)a.y; r[2] = (_Float16)a.z; r[3] = (_Float16)a.w;
    r[4] = (_Float16)b.x; r[5] = (_Float16)b.y; r[6] = (_Float16)b.z; r[7] = (_Float16)b.w;
    return r;
}

// ---------------- K0: weight transposes (Wq 2-level fp16, Wv/Wo 1-level fp16) ----------------
__global__ __launch_bounds__(256) void prep_w(const float* __restrict__ Wq,
                                              const float* __restrict__ Wv,
                                              const float* __restrict__ Wo,
                                              ushort_t* __restrict__ WqTh, ushort_t* __restrict__ WqTm,
                                              ushort_t* __restrict__ WvTh, ushort_t* __restrict__ WoTh) {
    __shared__ float tl[32][33];
    const int tid = threadIdx.x;
    const int b = blockIdx.x;
    const int mat = b >> 8;                // 0 Wq, 1 Wv, 2 Wo
    const int tile = b & 255;
    const int r0 = (tile >> 4) * 32;       // k rows
    const int c0 = (tile & 15) * 32;       // n cols
    const float* W = (mat == 0) ? Wq : ((mat == 1) ? Wv : Wo);
    const int rr = tid >> 3, cc = (tid & 7) * 4;
    *(float4*)&tl[rr][cc] = *(const float4*)(W + (size_t)(r0 + rr) * DD + c0 + cc);
    __syncthreads();
    float y[4];
#pragma unroll
    for (int i = 0; i < 4; ++i) y[i] = tl[cc + i][rr];
    size_t ob = (size_t)(c0 + rr) * DD + r0 + cc;
    if (mat == 0) {
        ushort_t h[4], m[4];
#pragma unroll
        for (int i = 0; i < 4; ++i) {
            h[i] = f16b(y[i]);
            m[i] = f16b((y[i] - f16tof(h[i])) * 2048.f);
        }
        store4u(WqTh + ob, h); store4u(WqTm + ob, m);
    } else {
        ushort_t h[4];
#pragma unroll
        for (int i = 0; i < 4; ++i) h[i] = f16b(y[i]);
        store4u((mat == 1 ? WvTh : WoTh) + ob, h);
    }
}

// ---------------- K1: projections + fused hash (identical to round 9) ----------------
__global__ __launch_bounds__(256) void gemm_hash(const float* __restrict__ query,
                                                 const float* __restrict__ value,
                                                 const ushort_t* __restrict__ WqTh,
                                                 const ushort_t* __restrict__ WqTm,
                                                 const ushort_t* __restrict__ WvTh,
                                                 const float* __restrict__ bq,
                                                 const float* __restrict__ bv,
                                                 const float* __restrict__ rnd,
                                                 float* __restrict__ Qf, float* __restrict__ Vf,
                                                 int* __restrict__ HASH, float* __restrict__ RNORM) {
    __shared__ __align__(16) char SM[24704];
    const int tid = threadIdx.x;
    const int b = blockIdx.x;
    const bool isQ = (b < 256);
    const int t = isQ ? b : b - 256;
    const int m0 = (t >> 3) * 32, n0 = (t & 7) * 64;
    const int wave = tid >> 6, lane = tid & 63;
    const int wm_ = wave & 1, wn_ = wave >> 1;
    const int arow = tid >> 3;
    const int abyte = arow * 64 + ((((tid & 7) >> 1) ^ (arow & 3)) << 4) + (tid & 1) * 8;
    const int brow = tid >> 2, bs = tid & 3;
    const int bbyte = brow * 64 + ((bs ^ (brow & 3)) << 4);
    const size_t gA = (size_t)(m0 + arow) * DD + (tid & 7) * 4;
    const size_t gB = (size_t)(n0 + brow) * DD + bs * 8;
    const int kb = lane >> 4;
    const int far_ = wm_ * 16 + (lane & 15);
    const int fabyte = far_ * 64 + ((kb ^ (far_ & 3)) << 4);
    int fbbyte[2];
#pragma unroll
    for (int j = 0; j < 2; ++j) {
        int c = wn_ * 32 + j * 16 + (lane & 15);
        fbbyte[j] = c * 64 + ((kb ^ (c & 3)) << 4);
    }
    const float* Asrc = isQ ? query : value;
    const ushort_t* Bh_src = isQ ? WqTh : WvTh;
    f32x4 acc0[2] = {};
    f32x4 acc1[2] = {};
    float4 xa = *(const float4*)(Asrc + gA);
    uint4 wh = *(const uint4*)(Bh_src + gB);
    uint4 wm = {};
    if (isQ) wm = *(const uint4*)(WqTm + gB);
    for (int kt = 0; kt < DD; kt += 32) {
        __syncthreads();
        {
            float xs[4] = {xa.x, xa.y, xa.z, xa.w};
            ushort_t h4[4];
#pragma unroll
            for (int i = 0; i < 4; ++i) h4[i] = f16b(xs[i]);
            store4u((ushort_t*)(SM + abyte), h4);
            if (isQ) {
                ushort_t m4[4];
#pragma unroll
                for (int i = 0; i < 4; ++i)
                    m4[i] = f16b((xs[i] - f16tof(h4[i])) * 2048.f);
                store4u((ushort_t*)(SM + 2048 + abyte), m4);
            }
            *(uint4*)(SM + 4096 + bbyte) = wh;
            if (isQ) *(uint4*)(SM + 8192 + bbyte) = wm;
        }
        __syncthreads();
        if (kt + 32 < DD) {
            xa = *(const float4*)(Asrc + gA + kt + 32);
            wh = *(const uint4*)(Bh_src + gB + kt + 32);
            if (isQ) wm = *(const uint4*)(WqTm + gB + kt + 32);
        }
        f16x8 ah = *(const f16x8*)(SM + fabyte);
        f16x8 bh0 = *(const f16x8*)(SM + 4096 + fbbyte[0]);
        f16x8 bh1 = *(const f16x8*)(SM + 4096 + fbbyte[1]);
        acc0[0] = __builtin_amdgcn_mfma_f32_16x16x32_f16(ah, bh0, acc0[0], 0, 0, 0);
        acc0[1] = __builtin_amdgcn_mfma_f32_16x16x32_f16(ah, bh1, acc0[1], 0, 0, 0);
        if (isQ) {
            f16x8 am = *(const f16x8*)(SM + 2048 + fabyte);
            f16x8 bm0 = *(const f16x8*)(SM + 8192 + fbbyte[0]);
            f16x8 bm1 = *(const f16x8*)(SM + 8192 + fbbyte[1]);
            acc1[0] = __builtin_amdgcn_mfma_f32_16x16x32_f16(ah, bm0, acc1[0], 0, 0, 0);
            acc1[0] = __builtin_amdgcn_mfma_f32_16x16x32_f16(am, bh0, acc1[0], 0, 0, 0);
            acc1[1] = __builtin_amdgcn_mfma_f32_16x16x32_f16(ah, bm1, acc1[1], 0, 0, 0);
            acc1[1] = __builtin_amdgcn_mfma_f32_16x16x32_f16(am, bh1, acc1[1], 0, 0, 0);
        }
    }
    __syncthreads();
    if (!isQ) {
#pragma unroll
        for (int j = 0; j < 2; ++j) {
            int cl = wn_ * 32 + j * 16 + (lane & 15);
            float bias_ = bv[n0 + cl];
#pragma unroll
            for (int reg = 0; reg < 4; ++reg) {
                int rl = wm_ * 16 + (lane >> 4) * 4 + reg;
                Vf[(size_t)n0 * LQ + (size_t)(m0 + rl) * DK + cl] = acc0[j][reg] + bias_;
            }
        }
        return;
    }
    float (*qtile)[65] = (float(*)[65])SM;
    float (*rmn)[64] = (float(*)[64])(SM + 8320);
#pragma unroll
    for (int j = 0; j < 2; ++j) {
        int cl = wn_ * 32 + j * 16 + (lane & 15);
        float bq_ = bq[n0 + cl];
#pragma unroll
        for (int reg = 0; reg < 4; ++reg) {
            int rl = wm_ * 16 + (lane >> 4) * 4 + reg;
            float x = acc0[j][reg] + acc1[j][reg] * (1.f / 2048.f) + bq_;
            Qf[(size_t)n0 * LQ + (size_t)(m0 + rl) * DK + cl] = x;
            qtile[rl][cl] = x;
        }
    }
    for (int idx = tid; idx < 4096; idx += 256)
        rmn[idx >> 6][idx & 63] = rnd[idx];
    __syncthreads();
    if (tid < 128) {
        int d = tid >> 1, rh = tid & 1;
        float s = 0.f;
        for (int j = 0; j < 32; ++j) { float x = rmn[d][rh * 32 + j]; s += x * x; }
        float nrm = sqrtf(s);
        for (int j = 0; j < 32; ++j) rmn[d][rh * 32 + j] = rmn[d][rh * 32 + j] / nrm;
    }
    __syncthreads();
    const int j = lane & 31, r = lane >> 5;
    const int bh = n0 >> 6;
    for (int it = 0; it < 8; ++it) {
        const int rl = it * 4 + wave;
        const int row = (bh << 10) + m0 + rl;
        float x = qtile[rl][lane];
        float s2 = x * x;
#pragma unroll
        for (int m = 1; m < 64; m <<= 1) s2 += __shfl_xor(s2, m);
        if (lane == 0) RNORM[row] = 1.0f / sqrtf(s2);
        float p0 = 0.f, p1 = 0.f, p2 = 0.f, p3 = 0.f;
#pragma unroll 4
        for (int d = 0; d < 64; d += 4) {
            p0 += __shfl(x, d + 0) * rmn[d + 0][lane];
            p1 += __shfl(x, d + 1) * rmn[d + 1][lane];
            p2 += __shfl(x, d + 2) * rmn[d + 2][lane];
            p3 += __shfl(x, d + 3) * rmn[d + 3][lane];
        }
        float p = (p0 + p1) + (p2 + p3);
        float bv_; int bi;
        if (p >= -p) { bv_ = p; bi = j; } else { bv_ = -p; bi = 32 + j; }
#pragma unroll
        for (int m = 1; m < 32; m <<= 1) {
            float ov = __shfl_xor(bv_, m);
            int oi = __shfl_xor(bi, m);
            if (ov > bv_ || (ov == bv_ && oi < bi)) { bv_ = ov; bi = oi; }
        }
        if (j == 0) HASH[((size_t)bh * RR + r) * LQ + m0 + rl] = bi;
    }
}

// ---------------- K2: stable counting sort per (bh, r) ----------------
__global__ __launch_bounds__(256) void sort_kernel(const int* __restrict__ HASH,
                                                   int* __restrict__ HIDX,
                                                   int* __restrict__ OIDX,
                                                   int* __restrict__ HSORT) {
    __shared__ __align__(16) char SM[39424];
    int* hl = (int*)SM;
    ushort_t (*cnt)[64] = (ushort_t(*)[64])(SM + 4096);
    int (*psum)[4] = (int(*)[4])(SM + 36864);
    int (*poff)[4] = (int(*)[4])(SM + 37888);
    int* base = (int*)(SM + 38912);
    const int tid = threadIdx.x;
    const int pair = blockIdx.x;
    const int* hsrc = HASH + (size_t)pair * LQ;
    for (int i = tid; i < 1024; i += 256) hl[i] = hsrc[i];
    int* cz = (int*)(SM + 4096);
    for (int i = tid; i < 8192; i += 256) cz[i] = 0;
    __syncthreads();
    for (int i = 0; i < 4; ++i) {
        int h = hl[tid * 4 + i];
        cnt[tid][h] += 1;
    }
    __syncthreads();
    {
        int h = tid >> 2, seg = tid & 3;
        int run = 0;
        for (int tt = seg * 64; tt < seg * 64 + 64; ++tt) {
            int tmp = cnt[tt][h];
            cnt[tt][h] = (ushort_t)run;
            run += tmp;
        }
        psum[h][seg] = run;
    }
    __syncthreads();
    if (tid < 64) {
        int run = 0;
#pragma unroll
        for (int seg = 0; seg < 4; ++seg) { int t = psum[tid][seg]; poff[tid][seg] = run; run += t; }
        int incl = run;
#pragma unroll
        for (int d = 1; d < 64; d <<= 1) {
            int y = __shfl_up(incl, d);
            if (tid >= d) incl += y;
        }
        base[tid] = incl - run;
    }
    __syncthreads();
    int* HI = HIDX + (size_t)pair * LQ;
    int* OI = OIDX + (size_t)pair * LQ;
    int* HS = HSORT + (size_t)pair * LQ;
    const int myseg = tid >> 6;
    for (int i = 0; i < 4; ++i) {
        int l = tid * 4 + i;
        int h = hl[l];
        int pos = base[h] + poff[h][myseg] + cnt[tid][h];
        cnt[tid][h] = (ushort_t)(cnt[tid][h] + 1);
        HI[pos] = l;
        OI[l] = pos;
        HS[pos] = h;
    }
}

// ---------------- K3: scores(MFMA fp16) + penalties(f32) + softmax partials + PV(MFMA fp16) ----
// LDS map: [0,17408) region A: Qh fp16 planes @0 (4K) + Kh fp16 planes @4096 (8K), later Vt f32 [64][68]
//          [17408,26112) Pf f32 [32][68]; [26112,26624) redm[32][4]; [26624,27136) redl[32][4]
//          [27136,28800) meta: qi_l,hsq,Aq (32 ea) ki_l,hsk,Ak,krn,lcnt (64 ea)
__global__ __launch_bounds__(256) void spv_kernel(const float* __restrict__ Q,
                                                  const float* __restrict__ RNORM,
                                                  const float* __restrict__ Vf,
                                                  const int* __restrict__ HIDX,
                                                  const int* __restrict__ OIDX,
                                                  const int* __restrict__ HSORT,
                                                  float* __restrict__ PV,
                                                  float2* __restrict__ ML) {
    const int n = blockIdx.x, r = blockIdx.y, bh = blockIdx.z;
    const int pair = bh * RR + r;
    __shared__ __align__(16) char SM[28800];
    float (*Vt)[68] = (float(*)[68])SM;
    float (*Pf)[68] = (float(*)[68])(SM + 17408);
    float (*redm)[4] = (float(*)[4])(SM + 26112);
    float (*redl)[4] = (float(*)[4])(SM + 26624);
    int* qi_l = (int*)(SM + 27136);
    int* hsq  = (int*)(SM + 27264);
    int* Aq   = (int*)(SM + 27392);
    int* ki_l = (int*)(SM + 27520);
    int* hsk  = (int*)(SM + 27776);
    int* Ak   = (int*)(SM + 28032);
    float* krn  = (float*)(SM + 28288);
    float* lcnt = (float*)(SM + 28544);
    const int tid = threadIdx.x;
    const int wave = tid >> 6, lane = tid & 63;
    const int la = lane & 15, gq = lane >> 4;
    const int* HI = HIDX + (size_t)pair * LQ;
    const int* OI = OIDX + (size_t)pair * LQ;
    const int* HS = HSORT + (size_t)pair * LQ;
    if (tid < 32) {
        int s = n * 32 + tid;
        qi_l[tid] = HI[s]; hsq[tid] = HS[s]; Aq[tid] = OI[s];
    } else if (tid < 96) {
        int k = tid - 32;
        int t = (n - 1) * 32 + k;
        if (t < 0) { ki_l[k] = -1; hsk[k] = 0; Ak[k] = 0; krn[k] = 0.f; }
        else {
            int ki = HI[t];
            ki_l[k] = ki; hsk[k] = HS[t]; Ak[k] = OI[t];
            krn[k] = RNORM[(size_t)bh * LQ + ki];
        }
    }
    __syncthreads();
    if (tid == 0) {
        if (n > 0) {
            for (int k = 0; k < 64; ++k) lcnt[k] = 0.f;
        } else {
            int zc = 0;
            for (int k = 32; k < 64; ++k) zc += (Ak[k] == 0);
            float l32 = logf((float)(32 + zc));
            for (int k = 0; k < 32; ++k) lcnt[k] = l32;
            for (int k = 32; k < 64; ++k) lcnt[k] = (Ak[k] == 0) ? l32 : 0.f;
        }
    }
    // stage Qh fp16 planes: thread -> (row = tid>>3, octet o = tid&7)
    {
        int row = tid >> 3, o = tid & 7;
        const float* src = Q + ((size_t)bh * LQ + qi_l[row]) * DK + o * 8;
        float4 u0 = ((const float4*)src)[0];
        float4 u1 = ((const float4*)src)[1];
        int p = o >> 2, s = o & 3;
        int sw = (row & 3) ^ ((row >> 2) & 3);
        *(uint4*)(SM + p * 2048 + row * 64 + ((s ^ sw) << 4)) = pku(u0, u1);
    }
    // stage Kh fp16 planes (scaled by krn): thread -> (row = tid>>2, o2 = tid&3)
    {
        int row = tid >> 2, o2 = tid & 3;
        int ki = ki_l[row];
        float rn = krn[row];
        float4 u0 = {0,0,0,0}, u1 = {0,0,0,0}, u2 = {0,0,0,0}, u3 = {0,0,0,0};
        if (ki >= 0) {
            const float* src = Q + ((size_t)bh * LQ + ki) * DK + o2 * 16;
            u0 = ((const float4*)src)[0]; u1 = ((const float4*)src)[1];
            u2 = ((const float4*)src)[2]; u3 = ((const float4*)src)[3];
            u0.x *= rn; u0.y *= rn; u0.z *= rn; u0.w *= rn;
            u1.x *= rn; u1.y *= rn; u1.z *= rn; u1.w *= rn;
            u2.x *= rn; u2.y *= rn; u2.z *= rn; u2.w *= rn;
            u3.x *= rn; u3.y *= rn; u3.z *= rn; u3.w *= rn;
        }
        int p = o2 >> 1, sb = (o2 & 1) * 2;
        int sw = (row & 3) ^ ((row >> 2) & 3);
        *(uint4*)(SM + 4096 + p * 4096 + row * 64 + ((sb ^ sw) << 4)) = pku(u0, u1);
        *(uint4*)(SM + 4096 + p * 4096 + row * 64 + (((sb + 1) ^ sw) << 4)) = pku(u2, u3);
    }
    __syncthreads();
    // QK^T: wave handles key-tile = wave (keys 16w..16w+15), 2 m-tiles, K=64 in 2 steps
    f32x4 accS[2] = {};
    {
        int rb = wave * 16 + la;
        int swb = (rb & 3) ^ ((rb >> 2) & 3);
        f16x8 bk[2], aq[2][2];
#pragma unroll
        for (int p = 0; p < 2; ++p)
            bk[p] = *(const f16x8*)(SM + 4096 + p * 4096 + rb * 64 + (((gq) ^ swb) << 4));
#pragma unroll
        for (int mf = 0; mf < 2; ++mf) {
            int ra = mf * 16 + la;
            int swa = (ra & 3) ^ ((ra >> 2) & 3);
#pragma unroll
            for (int p = 0; p < 2; ++p)
                aq[mf][p] = *(const f16x8*)(SM + p * 2048 + ra * 64 + (((gq) ^ swa) << 4));
        }
#pragma unroll
        for (int p = 0; p < 2; ++p)
#pragma unroll
            for (int mf = 0; mf < 2; ++mf)
                accS[mf] = __builtin_amdgcn_mfma_f32_16x16x32_f16(aq[mf][p], bk[p], accS[mf], 0, 0, 0);
    }
    // penalties (exact reference op order) + in-group row max
    const int key = wave * 16 + la;
    const int hk = hsk[key], ak = Ak[key];
    const float lc = lcnt[key];
    float sv[2][4], pmax[2][4];
#pragma unroll
    for (int mf = 0; mf < 2; ++mf)
#pragma unroll
        for (int reg = 0; reg < 4; ++reg) {
            int row = mf * 16 + gq * 4 + reg;
            int hq = hsq[row], aqv = Aq[row];
            float v = accS[mf][reg] * 0.125f;
            v = v - ((n == 0 && wave < 2) ? 1e9f : 0.f);   // lm pad
            v = v - ((hq == hk) ? 0.f : 1e9f);             // heq
            v = v - ((aqv > ak) ? 0.f : 1e9f);             // causal
            v = v - ((aqv == ak) ? 1e5f : 0.f);            // ieq
            v = v - lc;                                    // log(count)
            sv[mf][reg] = v;
            float pm = v;
#pragma unroll
            for (int m_ = 1; m_ < 16; m_ <<= 1) pm = fmaxf(pm, __shfl_xor(pm, m_));
            pmax[mf][reg] = pm;
        }
    if (la == 0) {
#pragma unroll
        for (int mf = 0; mf < 2; ++mf)
#pragma unroll
            for (int reg = 0; reg < 4; ++reg)
                redm[mf * 16 + gq * 4 + reg][wave] = pmax[mf][reg];
    }
    __syncthreads();                                       // Qh/Kh dead; redm complete
    // stage Vt f32 [dim][key] (overlay region A)
    for (int idx = tid; idx < 64 * 16; idx += 256) {
        int row = idx >> 4, c4 = idx & 15;
        int ki = ki_l[row];
        float4 v;
        if (ki < 0) { v.x = 0.f; v.y = 0.f; v.z = 0.f; v.w = 0.f; }
        else v = ((const float4*)(Vf + ((size_t)bh * LQ + ki) * DK))[c4];
        Vt[c4 * 4 + 0][row] = v.x; Vt[c4 * 4 + 1][row] = v.y;
        Vt[c4 * 4 + 2][row] = v.z; Vt[c4 * 4 + 3][row] = v.w;
    }
    // m, e, P write, row-sum partials
    float mrow[2][4], lsum[2][4];
#pragma unroll
    for (int mf = 0; mf < 2; ++mf)
#pragma unroll
        for (int reg = 0; reg < 4; ++reg) {
            int row = mf * 16 + gq * 4 + reg;
            float4 rm = *(const float4*)&redm[row][0];
            float m = fmaxf(fmaxf(rm.x, rm.y), fmaxf(rm.z, rm.w));
            mrow[mf][reg] = m;
            float e = expf(sv[mf][reg] - m);
            Pf[row][key] = e;
            float ps = e;
#pragma unroll
            for (int m_ = 1; m_ < 16; m_ <<= 1) ps += __shfl_xor(ps, m_);
            lsum[mf][reg] = ps;                            // partial (this wave's 16 keys)
        }
    if (la == 0) {
#pragma unroll
        for (int mf = 0; mf < 2; ++mf)
#pragma unroll
            for (int reg = 0; reg < 4; ++reg)
                redl[mf * 16 + gq * 4 + reg][wave] = lsum[mf][reg];
    }
    __syncthreads();                                       // Pf, redl, Vt complete
#pragma unroll
    for (int mf = 0; mf < 2; ++mf)
#pragma unroll
        for (int reg = 0; reg < 4; ++reg) {
            int row = mf * 16 + gq * 4 + reg;
            float4 rl = *(const float4*)&redl[row][0];
            lsum[mf][reg] = (rl.x + rl.y) + (rl.z + rl.w);
        }
    // PV: wave handles dim-tile = wave (dims 16w..16w+15)
    f32x4 accO[2] = {};
    {
        int dimr = wave * 16 + la;
        f16x8 bf2[2], af[2][2];
#pragma unroll
        for (int p = 0; p < 2; ++p) {
            const float* vsrc = &Vt[dimr][p * 32 + gq * 8];
            float4 b0 = *(const float4*)vsrc;
            float4 b1 = *(const float4*)(vsrc + 4);
            bf2[p] = pk8(b0, b1);
        }
#pragma unroll
        for (int mf = 0; mf < 2; ++mf) {
            int qrow = mf * 16 + la;
#pragma unroll
            for (int p = 0; p < 2; ++p) {
                const float* psrc = &Pf[qrow][p * 32 + gq * 8];
                float4 a0 = *(const float4*)psrc;
                float4 a1 = *(const float4*)(psrc + 4);
                af[mf][p] = pk8(a0, a1);
            }
        }
#pragma unroll
        for (int p = 0; p < 2; ++p)
#pragma unroll
            for (int mf = 0; mf < 2; ++mf)
                accO[mf] = __builtin_amdgcn_mfma_f32_16x16x32_f16(af[mf][p], bf2[p], accO[mf], 0, 0, 0);
    }
    // outputs
#pragma unroll
    for (int mf = 0; mf < 2; ++mf)
#pragma unroll
        for (int reg = 0; reg < 4; ++reg) {
            int row = mf * 16 + gq * 4 + reg;
            int srt = n * 32 + row;
            PV[(((size_t)pair * LQ + srt) << 6) + wave * 16 + la] = accO[mf][reg];
        }
    if (wave == 0 && la == 0) {
#pragma unroll
        for (int mf = 0; mf < 2; ++mf)
#pragma unroll
            for (int reg = 0; reg < 4; ++reg) {
                int row = mf * 16 + gq * 4 + reg;
                ML[(size_t)pair * LQ + n * 32 + row] = make_float2(mrow[mf][reg], lsum[mf][reg]);
            }
    }
}

// ---------------- K4: output projection (32x64 tiles, fp16) with fused combine ----------------
__global__ __launch_bounds__(256) void out_combine(const float* __restrict__ PV,
                                                   const float2* __restrict__ ML,
                                                   const int* __restrict__ OIDX,
                                                   const ushort_t* __restrict__ WoTh,
                                                   const float* __restrict__ bo,
                                                   float* __restrict__ out) {
    __shared__ __align__(16) char SM[6144];
    const int tid = threadIdx.x;
    const int b = blockIdx.x;
    const int m0 = (b >> 3) * 32, n0 = (b & 7) * 64;
    const int wave = tid >> 6, lane = tid & 63;
    const int wm_ = wave & 1, wn_ = wave >> 1;
    const int arow = tid >> 3;
    const int abyte = arow * 64 + ((((tid & 7) >> 1) ^ (arow & 3)) << 4) + (tid & 1) * 8;
    const int brow = tid >> 2, bs = tid & 3;
    const int bbyte = brow * 64 + ((bs ^ (brow & 3)) << 4);
    const size_t gB = (size_t)(n0 + brow) * DD + bs * 8;
    const int kb = lane >> 4;
    const int far_ = wm_ * 16 + (lane & 15);
    const int fabyte = far_ * 64 + ((kb ^ (far_ & 3)) << 4);
    int fbbyte[2];
#pragma unroll
    for (int j = 0; j < 2; ++j) {
        int c = wn_ * 32 + j * 16 + (lane & 15);
        fbbyte[j] = c * 64 + ((kb ^ (c & 3)) << 4);
    }
    const int l = m0 + arow;
    float4 a0, a1; float2 ml0, ml1;
    {
        int d0 = (tid & 7) * 4;
        size_t p0 = 0, p1 = 1;
        int s0 = OIDX[p0 * LQ + l], s1 = OIDX[p1 * LQ + l];
        ml0 = ML[p0 * LQ + s0]; ml1 = ML[p1 * LQ + s1];
        a0 = *(const float4*)(PV + ((p0 * LQ + s0) << 6) + d0);
        a1 = *(const float4*)(PV + ((p1 * LQ + s1) << 6) + d0);
    }
    uint4 whx = *(const uint4*)(WoTh + gB);
    f32x4 acc[2] = {};
    for (int kt = 0; kt < DD; kt += 32) {
        __syncthreads();
        {
            float M = fmaxf(ml0.x, ml1.x);
            float w0 = expf(ml0.x - M);
            float w1 = expf(ml1.x - M);
            float denom = w0 * ml0.y + w1 * ml1.y;
            float av0[4] = {a0.x, a0.y, a0.z, a0.w};
            float av1[4] = {a1.x, a1.y, a1.z, a1.w};
            ushort_t h4[4];
#pragma unroll
            for (int i = 0; i < 4; ++i)
                h4[i] = f16b((w0 * av0[i] + w1 * av1[i]) / denom);
            store4u((ushort_t*)(SM + abyte), h4);
            *(uint4*)(SM + 2048 + bbyte) = whx;
        }
        __syncthreads();
        if (kt + 32 < DD) {
            int ktn = kt + 32;
            int head = ktn >> 6;
            int d0 = (ktn & 63) + (tid & 7) * 4;
            size_t p0 = (size_t)head * RR, p1 = p0 + 1;
            int s0 = OIDX[p0 * LQ + l], s1 = OIDX[p1 * LQ + l];
            ml0 = ML[p0 * LQ + s0]; ml1 = ML[p1 * LQ + s1];
            a0 = *(const float4*)(PV + ((p0 * LQ + s0) << 6) + d0);
            a1 = *(const float4*)(PV + ((p1 * LQ + s1) << 6) + d0);
            whx = *(const uint4*)(WoTh + gB + ktn);
        }
        f16x8 ah = *(const f16x8*)(SM + fabyte);
        f16x8 bh0 = *(const f16x8*)(SM + 2048 + fbbyte[0]);
        f16x8 bh1 = *(const f16x8*)(SM + 2048 + fbbyte[1]);
        acc[0] = __builtin_amdgcn_mfma_f32_16x16x32_f16(ah, bh0, acc[0], 0, 0, 0);
        acc[1] = __builtin_amdgcn_mfma_f32_16x16x32_f16(ah, bh1, acc[1], 0, 0, 0);
    }
#pragma unroll
    for (int j = 0; j < 2; ++j) {
        int cl = wn_ * 32 + j * 16 + (lane & 15);
        float bb_ = bo[n0 + cl];
#pragma unroll
        for (int reg = 0; reg < 4; ++reg) {
            int rl = wm_ * 16 + (lane >> 4) * 4 + reg;
            out[(size_t)(m0 + rl) * DD + n0 + cl] = acc[j][reg] + bb_;
        }
    }
}

extern "C" void kernel_launch(void* const* d_in, const int* in_sizes, int n_in,
                              void* d_out, int out_size, void* d_ws, size_t ws_size,
                              hipStream_t stream) {
    const float* query = (const float*)d_in[0];
    const float* value = (const float*)d_in[2];
    const float* Wq = (const float*)d_in[4];
    const float* bq = (const float*)d_in[5];
    const float* Wv = (const float*)d_in[6];
    const float* bv = (const float*)d_in[7];
    const float* Wo = (const float*)d_in[8];
    const float* bo = (const float*)d_in[9];
    const float* rnd = (const float*)d_in[10];

    char* ws = (char*)d_ws;
    const size_t MB1 = 1u << 20;
    const size_t HK = 512u << 10;
    float*    Qf    = (float*)(ws);                       // [0,2MB)
    float*    Vf    = (float*)(ws + 2 * MB1);             // [2,4MB)
    float*    PV    = (float*)(ws + 4 * MB1);             // [4,8MB)
    ushort_t* WqTh  = (ushort_t*)(ws + 8 * MB1);
    ushort_t* WqTm  = (ushort_t*)(ws + 8 * MB1 + HK);
    ushort_t* WvTh  = (ushort_t*)(ws + 9 * MB1);
    ushort_t* WoTh  = (ushort_t*)(ws + 9 * MB1 + HK);
    float*    RNORM = (float*)(ws + 10 * MB1);
    char*     tail  = ws + 10 * MB1 + (64u << 10);
    int* HASH  = (int*)(tail);
    int* HIDX  = (int*)(tail + (64u << 10));
    int* OIDX  = (int*)(tail + (128u << 10));
    int* HSORT = (int*)(tail + (192u << 10));
    float2* ML = (float2*)(tail + (256u << 10));
    float* OUT = (float*)d_out;

    prep_w<<<768, 256, 0, stream>>>(Wq, Wv, Wo, WqTh, WqTm, WvTh, WoTh);
    gemm_hash<<<512, 256, 0, stream>>>(query, value, WqTh, WqTm, WvTh, bq, bv, rnd,
                                       Qf, Vf, HASH, RNORM);
    sort_kernel<<<16, 256, 0, stream>>>(HASH, HIDX, OIDX, HSORT);
    spv_kernel<<<dim3(32, 2, 8), 256, 0, stream>>>(Qf, RNORM, Vf, HIDX, OIDX, HSORT, PV, ML);
    out_combine<<<256, 256, 0, stream>>>(PV, ML, OIDX, WoTh, bo, OUT);
}

// Round 11
// 65.417 us; speedup vs baseline: 6.5228x; 1.0861x over previous
//
#include <hip/hip_runtime.h>
#include <math.h>

#define LQ 1024
#define DD 512
#define DK 64
#define RR 2

typedef unsigned short ushort_t;
typedef __attribute__((ext_vector_type(8))) _Float16 f16x8;
typedef __attribute__((ext_vector_type(4))) float f32x4;

__device__ inline ushort_t f16b(float x) {
    union { _Float16 h; ushort_t u; } c; c.h = (_Float16)x; return c.u;
}
__device__ inline float f16tof(ushort_t u) {
    union { ushort_t u; _Float16 h; } c; c.u = u; return (float)c.h;
}
__device__ inline void store4u(ushort_t* p, const ushort_t h[4]) {
    uint2 v;
    v.x = h[0] | ((unsigned int)h[1] << 16); v.y = h[2] | ((unsigned int)h[3] << 16);
    *(uint2*)p = v;
}
__device__ inline uint4 pku(float4 a, float4 b) {
    uint4 v;
    v.x = (unsigned)f16b(a.x) | ((unsigned)f16b(a.y) << 16);
    v.y = (unsigned)f16b(a.z) | ((unsigned)f16b(a.w) << 16);
    v.z = (unsigned)f16b(b.x) | ((unsigned)f16b(b.y) << 16);
    v.w = (unsigned)f16b(b.z) | ((unsigned)f16b(b.w) << 16);
    return v;
}
__device__ inline f16x8 pk8(float4 a, float4 b) {
    f16x8 r;
    r[0] = (_Float16)a.x; r[1] = (_Float16)a.y; r[2] = (_Float16)a.z; r[3] = (_Float16)a.w;
    r[4] = (_Float16)b.x; r[5] = (_Float16)b.y; r[6] = (_Float16)b.z; r[7] = (_Float16)b.w;
    return r;
}

// ---------------- K0: weight transposes (Wq 2-level fp16, Wv/Wo 1-level fp16) ----------------
__global__ __launch_bounds__(256) void prep_w(const float* __restrict__ Wq,
                                              const float* __restrict__ Wv,
                                              const float* __restrict__ Wo,
                                              ushort_t* __restrict__ WqTh, ushort_t* __restrict__ WqTm,
                                              ushort_t* __restrict__ WvTh, ushort_t* __restrict__ WoTh) {
    __shared__ float tl[32][33];
    const int tid = threadIdx.x;
    const int b = blockIdx.x;
    const int mat = b >> 8;                // 0 Wq, 1 Wv, 2 Wo
    const int tile = b & 255;
    const int r0 = (tile >> 4) * 32;       // k rows
    const int c0 = (tile & 15) * 32;       // n cols
    const float* W = (mat == 0) ? Wq : ((mat == 1) ? Wv : Wo);
    const int rr = tid >> 3, cc = (tid & 7) * 4;
    *(float4*)&tl[rr][cc] = *(const float4*)(W + (size_t)(r0 + rr) * DD + c0 + cc);
    __syncthreads();
    float y[4];
#pragma unroll
    for (int i = 0; i < 4; ++i) y[i] = tl[cc + i][rr];
    size_t ob = (size_t)(c0 + rr) * DD + r0 + cc;
    if (mat == 0) {
        ushort_t h[4], m[4];
#pragma unroll
        for (int i = 0; i < 4; ++i) {
            h[i] = f16b(y[i]);
            m[i] = f16b((y[i] - f16tof(h[i])) * 2048.f);
        }
        store4u(WqTh + ob, h); store4u(WqTm + ob, m);
    } else {
        ushort_t h[4];
#pragma unroll
        for (int i = 0; i < 4; ++i) h[i] = f16b(y[i]);
        store4u((mat == 1 ? WvTh : WoTh) + ob, h);
    }
}

// ---------------- K1: projections + fused hash; BK=64, double-buffered LDS, 1 barrier/step ----
// blocks [0,256): Q both fp16-split passes + fused hash epilogue. [256,512): V single pass.
__global__ __launch_bounds__(256) void gemm_hash(const float* __restrict__ query,
                                                 const float* __restrict__ value,
                                                 const ushort_t* __restrict__ WqTh,
                                                 const ushort_t* __restrict__ WqTm,
                                                 const ushort_t* __restrict__ WvTh,
                                                 const float* __restrict__ bq,
                                                 const float* __restrict__ bv,
                                                 const float* __restrict__ rnd,
                                                 float* __restrict__ Qf, float* __restrict__ Vf,
                                                 int* __restrict__ HASH, float* __restrict__ RNORM) {
    // per buffer (24576 B): Ah@0(4K) Am@4096(4K) Bh@8192(8K) Bm@16384(8K); 2 buffers
    // epilogue overlay: qtile[32][65]@0 (8320 B), rmn[64][64]@8320 (16384 B)
    __shared__ __align__(16) char SM[49152];
    const int tid = threadIdx.x;
    const int b = blockIdx.x;
    const bool isQ = (b < 256);
    const int t = isQ ? b : b - 256;
    const int m0 = (t >> 3) * 32, n0 = (t & 7) * 64;
    const int wave = tid >> 6, lane = tid & 63;
    const int wm_ = wave & 1, wn_ = wave >> 1;
    const int la = lane & 15, gq = lane >> 4;
    // staging coords (64-k tiles, row stride 128 B, slot^row swizzle)
    const int arow = tid >> 3, aoct = tid & 7;
    const int abyte = arow * 128 + ((aoct ^ (arow & 7)) << 4);
    const int brow = tid >> 2, bslot = (tid & 3) * 2;
    const int bbyte0 = brow * 128 + ((bslot ^ (brow & 7)) << 4);
    const int bbyte1 = brow * 128 + (((bslot + 1) ^ (brow & 7)) << 4);
    const size_t gA = (size_t)(m0 + arow) * DD + aoct * 8;
    const size_t gB = (size_t)(n0 + brow) * DD + bslot * 8;
    // fragment byte offsets
    const int farow = wm_ * 16 + la;
    int fA[2], fB[2][2];
#pragma unroll
    for (int p2 = 0; p2 < 2; ++p2)
        fA[p2] = farow * 128 + (((p2 * 4 + gq) ^ (farow & 7)) << 4);
#pragma unroll
    for (int j = 0; j < 2; ++j) {
        int c = wn_ * 32 + j * 16 + la;
#pragma unroll
        for (int p2 = 0; p2 < 2; ++p2)
            fB[j][p2] = c * 128 + (((p2 * 4 + gq) ^ (c & 7)) << 4);
    }
    const float* Asrc = isQ ? query : value;
    const ushort_t* Bh_src = isQ ? WqTh : WvTh;
    f32x4 acc0[2] = {}, acc1[2] = {};
    float4 xa0 = *(const float4*)(Asrc + gA);
    float4 xa1 = *(const float4*)(Asrc + gA + 4);
    uint4 wh0 = *(const uint4*)(Bh_src + gB);
    uint4 wh1 = *(const uint4*)(Bh_src + gB + 8);
    uint4 wm0 = {}, wm1 = {};
    if (isQ) { wm0 = *(const uint4*)(WqTm + gB); wm1 = *(const uint4*)(WqTm + gB + 8); }
    auto STAGE = [&](int pb) {
        char* base = SM + pb * 24576;
        *(uint4*)(base + abyte) = pku(xa0, xa1);
        if (isQ) {
            float4 r0, r1;
            r0.x = (xa0.x - f16tof(f16b(xa0.x))) * 2048.f;
            r0.y = (xa0.y - f16tof(f16b(xa0.y))) * 2048.f;
            r0.z = (xa0.z - f16tof(f16b(xa0.z))) * 2048.f;
            r0.w = (xa0.w - f16tof(f16b(xa0.w))) * 2048.f;
            r1.x = (xa1.x - f16tof(f16b(xa1.x))) * 2048.f;
            r1.y = (xa1.y - f16tof(f16b(xa1.y))) * 2048.f;
            r1.z = (xa1.z - f16tof(f16b(xa1.z))) * 2048.f;
            r1.w = (xa1.w - f16tof(f16b(xa1.w))) * 2048.f;
            *(uint4*)(base + 4096 + abyte) = pku(r0, r1);
        }
        *(uint4*)(base + 8192 + bbyte0) = wh0;
        *(uint4*)(base + 8192 + bbyte1) = wh1;
        if (isQ) {
            *(uint4*)(base + 16384 + bbyte0) = wm0;
            *(uint4*)(base + 16384 + bbyte1) = wm1;
        }
    };
    STAGE(0);
    int p = 0;
    for (int kt = 0; kt < DD; kt += 64) {
        __syncthreads();
        const bool more = (kt + 64 < DD);
        if (more) {
            xa0 = *(const float4*)(Asrc + gA + kt + 64);
            xa1 = *(const float4*)(Asrc + gA + kt + 68);
            wh0 = *(const uint4*)(Bh_src + gB + kt + 64);
            wh1 = *(const uint4*)(Bh_src + gB + kt + 72);
            if (isQ) {
                wm0 = *(const uint4*)(WqTm + gB + kt + 64);
                wm1 = *(const uint4*)(WqTm + gB + kt + 72);
            }
        }
        char* base = SM + p * 24576;
#pragma unroll
        for (int p2 = 0; p2 < 2; ++p2) {
            f16x8 ah = *(const f16x8*)(base + fA[p2]);
            f16x8 bh0 = *(const f16x8*)(base + 8192 + fB[0][p2]);
            f16x8 bh1 = *(const f16x8*)(base + 8192 + fB[1][p2]);
            acc0[0] = __builtin_amdgcn_mfma_f32_16x16x32_f16(ah, bh0, acc0[0], 0, 0, 0);
            acc0[1] = __builtin_amdgcn_mfma_f32_16x16x32_f16(ah, bh1, acc0[1], 0, 0, 0);
            if (isQ) {
                f16x8 am = *(const f16x8*)(base + 4096 + fA[p2]);
                f16x8 bm0 = *(const f16x8*)(base + 16384 + fB[0][p2]);
                f16x8 bm1 = *(const f16x8*)(base + 16384 + fB[1][p2]);
                acc1[0] = __builtin_amdgcn_mfma_f32_16x16x32_f16(ah, bm0, acc1[0], 0, 0, 0);
                acc1[0] = __builtin_amdgcn_mfma_f32_16x16x32_f16(am, bh0, acc1[0], 0, 0, 0);
                acc1[1] = __builtin_amdgcn_mfma_f32_16x16x32_f16(ah, bm1, acc1[1], 0, 0, 0);
                acc1[1] = __builtin_amdgcn_mfma_f32_16x16x32_f16(am, bh1, acc1[1], 0, 0, 0);
            }
        }
        if (more) STAGE(p ^ 1);
        p ^= 1;
    }
    __syncthreads();                             // all fragment reads done; LDS reusable
    if (!isQ) {
#pragma unroll
        for (int j = 0; j < 2; ++j) {
            int cl = wn_ * 32 + j * 16 + la;
            float bias_ = bv[n0 + cl];
#pragma unroll
            for (int reg = 0; reg < 4; ++reg) {
                int rl = wm_ * 16 + gq * 4 + reg;
                Vf[(size_t)n0 * LQ + (size_t)(m0 + rl) * DK + cl] = acc0[j][reg] + bias_;
            }
        }
        return;
    }
    // ---- Q epilogue: combine passes, store Qf, fused hash (bit-identical to round 10) ----
    float (*qtile)[65] = (float(*)[65])SM;
    float (*rmn)[64] = (float(*)[64])(SM + 8320);
#pragma unroll
    for (int j = 0; j < 2; ++j) {
        int cl = wn_ * 32 + j * 16 + la;
        float bq_ = bq[n0 + cl];
#pragma unroll
        for (int reg = 0; reg < 4; ++reg) {
            int rl = wm_ * 16 + gq * 4 + reg;
            float x = acc0[j][reg] + acc1[j][reg] * (1.f / 2048.f) + bq_;
            Qf[(size_t)n0 * LQ + (size_t)(m0 + rl) * DK + cl] = x;
            qtile[rl][cl] = x;
        }
    }
    for (int idx = tid; idx < 4096; idx += 256)
        rmn[idx >> 6][idx & 63] = rnd[idx];
    __syncthreads();
    if (tid < 128) {
        int d = tid >> 1, rh = tid & 1;
        float s = 0.f;
        for (int j = 0; j < 32; ++j) { float x = rmn[d][rh * 32 + j]; s += x * x; }
        float nrm = sqrtf(s);
        for (int j = 0; j < 32; ++j) rmn[d][rh * 32 + j] = rmn[d][rh * 32 + j] / nrm;
    }
    __syncthreads();
    const int j = lane & 31, r = lane >> 5;
    const int bh = n0 >> 6;
    for (int it = 0; it < 8; ++it) {
        const int rl = it * 4 + wave;
        const int row = (bh << 10) + m0 + rl;
        float x = qtile[rl][lane];
        float s2 = x * x;
#pragma unroll
        for (int m = 1; m < 64; m <<= 1) s2 += __shfl_xor(s2, m);
        if (lane == 0) RNORM[row] = 1.0f / sqrtf(s2);
        float p0 = 0.f, p1 = 0.f, p2 = 0.f, p3 = 0.f;
#pragma unroll 4
        for (int d = 0; d < 64; d += 4) {
            p0 += __shfl(x, d + 0) * rmn[d + 0][lane];
            p1 += __shfl(x, d + 1) * rmn[d + 1][lane];
            p2 += __shfl(x, d + 2) * rmn[d + 2][lane];
            p3 += __shfl(x, d + 3) * rmn[d + 3][lane];
        }
        float pr = (p0 + p1) + (p2 + p3);
        float bv_; int bi;
        if (pr >= -pr) { bv_ = pr; bi = j; } else { bv_ = -pr; bi = 32 + j; }
#pragma unroll
        for (int m = 1; m < 32; m <<= 1) {
            float ov = __shfl_xor(bv_, m);
            int oi = __shfl_xor(bi, m);
            if (ov > bv_ || (ov == bv_ && oi < bi)) { bv_ = ov; bi = oi; }
        }
        if (j == 0) HASH[((size_t)bh * RR + r) * LQ + m0 + rl] = bi;
    }
}

// ---------------- K2: stable counting sort per (bh, r) ----------------
__global__ __launch_bounds__(256) void sort_kernel(const int* __restrict__ HASH,
                                                   int* __restrict__ HIDX,
                                                   int* __restrict__ OIDX,
                                                   int* __restrict__ HSORT) {
    __shared__ __align__(16) char SM[39424];
    int* hl = (int*)SM;
    ushort_t (*cnt)[64] = (ushort_t(*)[64])(SM + 4096);
    int (*psum)[4] = (int(*)[4])(SM + 36864);
    int (*poff)[4] = (int(*)[4])(SM + 37888);
    int* base = (int*)(SM + 38912);
    const int tid = threadIdx.x;
    const int pair = blockIdx.x;
    const int* hsrc = HASH + (size_t)pair * LQ;
    for (int i = tid; i < 1024; i += 256) hl[i] = hsrc[i];
    int* cz = (int*)(SM + 4096);
    for (int i = tid; i < 8192; i += 256) cz[i] = 0;
    __syncthreads();
    for (int i = 0; i < 4; ++i) {
        int h = hl[tid * 4 + i];
        cnt[tid][h] += 1;
    }
    __syncthreads();
    {
        int h = tid >> 2, seg = tid & 3;
        int run = 0;
        for (int tt = seg * 64; tt < seg * 64 + 64; ++tt) {
            int tmp = cnt[tt][h];
            cnt[tt][h] = (ushort_t)run;
            run += tmp;
        }
        psum[h][seg] = run;
    }
    __syncthreads();
    if (tid < 64) {
        int run = 0;
#pragma unroll
        for (int seg = 0; seg < 4; ++seg) { int t = psum[tid][seg]; poff[tid][seg] = run; run += t; }
        int incl = run;
#pragma unroll
        for (int d = 1; d < 64; d <<= 1) {
            int y = __shfl_up(incl, d);
            if (tid >= d) incl += y;
        }
        base[tid] = incl - run;
    }
    __syncthreads();
    int* HI = HIDX + (size_t)pair * LQ;
    int* OI = OIDX + (size_t)pair * LQ;
    int* HS = HSORT + (size_t)pair * LQ;
    const int myseg = tid >> 6;
    for (int i = 0; i < 4; ++i) {
        int l = tid * 4 + i;
        int h = hl[l];
        int pos = base[h] + poff[h][myseg] + cnt[tid][h];
        cnt[tid][h] = (ushort_t)(cnt[tid][h] + 1);
        HI[pos] = l;
        OI[l] = pos;
        HS[pos] = h;
    }
}

// ---------------- K3: scores(MFMA fp16) + penalties(f32) + softmax partials + PV(MFMA fp16) ----
__global__ __launch_bounds__(256) void spv_kernel(const float* __restrict__ Q,
                                                  const float* __restrict__ RNORM,
                                                  const float* __restrict__ Vf,
                                                  const int* __restrict__ HIDX,
                                                  const int* __restrict__ OIDX,
                                                  const int* __restrict__ HSORT,
                                                  float* __restrict__ PV,
                                                  float2* __restrict__ ML) {
    const int n = blockIdx.x, r = blockIdx.y, bh = blockIdx.z;
    const int pair = bh * RR + r;
    __shared__ __align__(16) char SM[28800];
    float (*Vt)[68] = (float(*)[68])SM;
    float (*Pf)[68] = (float(*)[68])(SM + 17408);
    float (*redm)[4] = (float(*)[4])(SM + 26112);
    float (*redl)[4] = (float(*)[4])(SM + 26624);
    int* qi_l = (int*)(SM + 27136);
    int* hsq  = (int*)(SM + 27264);
    int* Aq   = (int*)(SM + 27392);
    int* ki_l = (int*)(SM + 27520);
    int* hsk  = (int*)(SM + 27776);
    int* Ak   = (int*)(SM + 28032);
    float* krn  = (float*)(SM + 28288);
    float* lcnt = (float*)(SM + 28544);
    const int tid = threadIdx.x;
    const int wave = tid >> 6, lane = tid & 63;
    const int la = lane & 15, gq = lane >> 4;
    const int* HI = HIDX + (size_t)pair * LQ;
    const int* OI = OIDX + (size_t)pair * LQ;
    const int* HS = HSORT + (size_t)pair * LQ;
    if (tid < 32) {
        int s = n * 32 + tid;
        qi_l[tid] = HI[s]; hsq[tid] = HS[s]; Aq[tid] = OI[s];
    } else if (tid < 96) {
        int k = tid - 32;
        int t = (n - 1) * 32 + k;
        if (t < 0) { ki_l[k] = -1; hsk[k] = 0; Ak[k] = 0; krn[k] = 0.f; }
        else {
            int ki = HI[t];
            ki_l[k] = ki; hsk[k] = HS[t]; Ak[k] = OI[t];
            krn[k] = RNORM[(size_t)bh * LQ + ki];
        }
    }
    __syncthreads();
    if (tid == 0) {
        if (n > 0) {
            for (int k = 0; k < 64; ++k) lcnt[k] = 0.f;
        } else {
            int zc = 0;
            for (int k = 32; k < 64; ++k) zc += (Ak[k] == 0);
            float l32 = logf((float)(32 + zc));
            for (int k = 0; k < 32; ++k) lcnt[k] = l32;
            for (int k = 32; k < 64; ++k) lcnt[k] = (Ak[k] == 0) ? l32 : 0.f;
        }
    }
    {
        int row = tid >> 3, o = tid & 7;
        const float* src = Q + ((size_t)bh * LQ + qi_l[row]) * DK + o * 8;
        float4 u0 = ((const float4*)src)[0];
        float4 u1 = ((const float4*)src)[1];
        int p = o >> 2, s = o & 3;
        int sw = (row & 3) ^ ((row >> 2) & 3);
        *(uint4*)(SM + p * 2048 + row * 64 + ((s ^ sw) << 4)) = pku(u0, u1);
    }
    {
        int row = tid >> 2, o2 = tid & 3;
        int ki = ki_l[row];
        float rn = krn[row];
        float4 u0 = {0,0,0,0}, u1 = {0,0,0,0}, u2 = {0,0,0,0}, u3 = {0,0,0,0};
        if (ki >= 0) {
            const float* src = Q + ((size_t)bh * LQ + ki) * DK + o2 * 16;
            u0 = ((const float4*)src)[0]; u1 = ((const float4*)src)[1];
            u2 = ((const float4*)src)[2]; u3 = ((const float4*)src)[3];
            u0.x *= rn; u0.y *= rn; u0.z *= rn; u0.w *= rn;
            u1.x *= rn; u1.y *= rn; u1.z *= rn; u1.w *= rn;
            u2.x *= rn; u2.y *= rn; u2.z *= rn; u2.w *= rn;
            u3.x *= rn; u3.y *= rn; u3.z *= rn; u3.w *= rn;
        }
        int p = o2 >> 1, sb = (o2 & 1) * 2;
        int sw = (row & 3) ^ ((row >> 2) & 3);
        *(uint4*)(SM + 4096 + p * 4096 + row * 64 + ((sb ^ sw) << 4)) = pku(u0, u1);
        *(uint4*)(SM + 4096 + p * 4096 + row * 64 + (((sb + 1) ^ sw) << 4)) = pku(u2, u3);
    }
    __syncthreads();
    f32x4 accS[2] = {};
    {
        int rb = wave * 16 + la;
        int swb = (rb & 3) ^ ((rb >> 2) & 3);
        f16x8 bk[2], aq[2][2];
#pragma unroll
        for (int p = 0; p < 2; ++p)
            bk[p] = *(const f16x8*)(SM + 4096 + p * 4096 + rb * 64 + (((gq) ^ swb) << 4));
#pragma unroll
        for (int mf = 0; mf < 2; ++mf) {
            int ra = mf * 16 + la;
            int swa = (ra & 3) ^ ((ra >> 2) & 3);
#pragma unroll
            for (int p = 0; p < 2; ++p)
                aq[mf][p] = *(const f16x8*)(SM + p * 2048 + ra * 64 + (((gq) ^ swa) << 4));
        }
#pragma unroll
        for (int p = 0; p < 2; ++p)
#pragma unroll
            for (int mf = 0; mf < 2; ++mf)
                accS[mf] = __builtin_amdgcn_mfma_f32_16x16x32_f16(aq[mf][p], bk[p], accS[mf], 0, 0, 0);
    }
    const int key = wave * 16 + la;
    const int hk = hsk[key], ak = Ak[key];
    const float lc = lcnt[key];
    float sv[2][4], pmax[2][4];
#pragma unroll
    for (int mf = 0; mf < 2; ++mf)
#pragma unroll
        for (int reg = 0; reg < 4; ++reg) {
            int row = mf * 16 + gq * 4 + reg;
            int hq = hsq[row], aqv = Aq[row];
            float v = accS[mf][reg] * 0.125f;
            v = v - ((n == 0 && wave < 2) ? 1e9f : 0.f);
            v = v - ((hq == hk) ? 0.f : 1e9f);
            v = v - ((aqv > ak) ? 0.f : 1e9f);
            v = v - ((aqv == ak) ? 1e5f : 0.f);
            v = v - lc;
            sv[mf][reg] = v;
            float pm = v;
#pragma unroll
            for (int m_ = 1; m_ < 16; m_ <<= 1) pm = fmaxf(pm, __shfl_xor(pm, m_));
            pmax[mf][reg] = pm;
        }
    if (la == 0) {
#pragma unroll
        for (int mf = 0; mf < 2; ++mf)
#pragma unroll
            for (int reg = 0; reg < 4; ++reg)
                redm[mf * 16 + gq * 4 + reg][wave] = pmax[mf][reg];
    }
    __syncthreads();
    for (int idx = tid; idx < 64 * 16; idx += 256) {
        int row = idx >> 4, c4 = idx & 15;
        int ki = ki_l[row];
        float4 v;
        if (ki < 0) { v.x = 0.f; v.y = 0.f; v.z = 0.f; v.w = 0.f; }
        else v = ((const float4*)(Vf + ((size_t)bh * LQ + ki) * DK))[c4];
        Vt[c4 * 4 + 0][row] = v.x; Vt[c4 * 4 + 1][row] = v.y;
        Vt[c4 * 4 + 2][row] = v.z; Vt[c4 * 4 + 3][row] = v.w;
    }
    float mrow[2][4], lsum[2][4];
#pragma unroll
    for (int mf = 0; mf < 2; ++mf)
#pragma unroll
        for (int reg = 0; reg < 4; ++reg) {
            int row = mf * 16 + gq * 4 + reg;
            float4 rm = *(const float4*)&redm[row][0];
            float m = fmaxf(fmaxf(rm.x, rm.y), fmaxf(rm.z, rm.w));
            mrow[mf][reg] = m;
            float e = expf(sv[mf][reg] - m);
            Pf[row][key] = e;
            float ps = e;
#pragma unroll
            for (int m_ = 1; m_ < 16; m_ <<= 1) ps += __shfl_xor(ps, m_);
            lsum[mf][reg] = ps;
        }
    if (la == 0) {
#pragma unroll
        for (int mf = 0; mf < 2; ++mf)
#pragma unroll
            for (int reg = 0; reg < 4; ++reg)
                redl[mf * 16 + gq * 4 + reg][wave] = lsum[mf][reg];
    }
    __syncthreads();
#pragma unroll
    for (int mf = 0; mf < 2; ++mf)
#pragma unroll
        for (int reg = 0; reg < 4; ++reg) {
            int row = mf * 16 + gq * 4 + reg;
            float4 rl = *(const float4*)&redl[row][0];
            lsum[mf][reg] = (rl.x + rl.y) + (rl.z + rl.w);
        }
    f32x4 accO[2] = {};
    {
        int dimr = wave * 16 + la;
        f16x8 bf2[2], af[2][2];
#pragma unroll
        for (int p = 0; p < 2; ++p) {
            const float* vsrc = &Vt[dimr][p * 32 + gq * 8];
            float4 b0 = *(const float4*)vsrc;
            float4 b1 = *(const float4*)(vsrc + 4);
            bf2[p] = pk8(b0, b1);
        }
#pragma unroll
        for (int mf = 0; mf < 2; ++mf) {
            int qrow = mf * 16 + la;
#pragma unroll
            for (int p = 0; p < 2; ++p) {
                const float* psrc = &Pf[qrow][p * 32 + gq * 8];
                float4 a0 = *(const float4*)psrc;
                float4 a1 = *(const float4*)(psrc + 4);
                af[mf][p] = pk8(a0, a1);
            }
        }
#pragma unroll
        for (int p = 0; p < 2; ++p)
#pragma unroll
            for (int mf = 0; mf < 2; ++mf)
                accO[mf] = __builtin_amdgcn_mfma_f32_16x16x32_f16(af[mf][p], bf2[p], accO[mf], 0, 0, 0);
    }
#pragma unroll
    for (int mf = 0; mf < 2; ++mf)
#pragma unroll
        for (int reg = 0; reg < 4; ++reg) {
            int row = mf * 16 + gq * 4 + reg;
            int srt = n * 32 + row;
            PV[(((size_t)pair * LQ + srt) << 6) + wave * 16 + la] = accO[mf][reg];
        }
    if (wave == 0 && la == 0) {
#pragma unroll
        for (int mf = 0; mf < 2; ++mf)
#pragma unroll
            for (int reg = 0; reg < 4; ++reg) {
                int row = mf * 16 + gq * 4 + reg;
                ML[(size_t)pair * LQ + n * 32 + row] = make_float2(mrow[mf][reg], lsum[mf][reg]);
            }
    }
}

// ---------------- K4: output projection, BK=64, double-buffered, fused combine ----------------
__global__ __launch_bounds__(256) void out_combine(const float* __restrict__ PV,
                                                   const float2* __restrict__ ML,
                                                   const int* __restrict__ OIDX,
                                                   const ushort_t* __restrict__ WoTh,
                                                   const float* __restrict__ bo,
                                                   float* __restrict__ out) {
    // per buffer (12288 B): Ah@0(4K) Bh@4096(8K); 2 buffers
    __shared__ __align__(16) char SM[24576];
    const int tid = threadIdx.x;
    const int b = blockIdx.x;
    const int m0 = (b >> 3) * 32, n0 = (b & 7) * 64;
    const int wave = tid >> 6, lane = tid & 63;
    const int wm_ = wave & 1, wn_ = wave >> 1;
    const int la = lane & 15, gq = lane >> 4;
    const int arow = tid >> 3, aoct = tid & 7;
    const int abyte = arow * 128 + ((aoct ^ (arow & 7)) << 4);
    const int brow = tid >> 2, bslot = (tid & 3) * 2;
    const int bbyte0 = brow * 128 + ((bslot ^ (brow & 7)) << 4);
    const int bbyte1 = brow * 128 + (((bslot + 1) ^ (brow & 7)) << 4);
    const size_t gB = (size_t)(n0 + brow) * DD + bslot * 8;
    const int farow = wm_ * 16 + la;
    int fA[2], fB[2][2];
#pragma unroll
    for (int p2 = 0; p2 < 2; ++p2)
        fA[p2] = farow * 128 + (((p2 * 4 + gq) ^ (farow & 7)) << 4);
#pragma unroll
    for (int j = 0; j < 2; ++j) {
        int c = wn_ * 32 + j * 16 + la;
#pragma unroll
        for (int p2 = 0; p2 < 2; ++p2)
            fB[j][p2] = c * 128 + (((p2 * 4 + gq) ^ (c & 7)) << 4);
    }
    const int l = m0 + arow;
    float4 a00, a01, a10, a11; float2 ml0, ml1;
    auto FETCH = [&](int h) {
        size_t p0 = (size_t)h * RR, p1 = p0 + 1;
        int s0 = OIDX[p0 * LQ + l], s1 = OIDX[p1 * LQ + l];
        ml0 = ML[p0 * LQ + s0]; ml1 = ML[p1 * LQ + s1];
        const float* q0 = PV + ((p0 * LQ + s0) << 6) + aoct * 8;
        const float* q1 = PV + ((p1 * LQ + s1) << 6) + aoct * 8;
        a00 = ((const float4*)q0)[0]; a01 = ((const float4*)q0)[1];
        a10 = ((const float4*)q1)[0]; a11 = ((const float4*)q1)[1];
    };
    uint4 wh0 = *(const uint4*)(WoTh + gB);
    uint4 wh1 = *(const uint4*)(WoTh + gB + 8);
    FETCH(0);
    auto STAGE = [&](int pb) {
        char* base = SM + pb * 12288;
        float M = fmaxf(ml0.x, ml1.x);
        float w0 = expf(ml0.x - M);
        float w1 = expf(ml1.x - M);
        float denom = w0 * ml0.y + w1 * ml1.y;
        float4 c0, c1;
        c0.x = (w0 * a00.x + w1 * a10.x) / denom;
        c0.y = (w0 * a00.y + w1 * a10.y) / denom;
        c0.z = (w0 * a00.z + w1 * a10.z) / denom;
        c0.w = (w0 * a00.w + w1 * a10.w) / denom;
        c1.x = (w0 * a01.x + w1 * a11.x) / denom;
        c1.y = (w0 * a01.y + w1 * a11.y) / denom;
        c1.z = (w0 * a01.z + w1 * a11.z) / denom;
        c1.w = (w0 * a01.w + w1 * a11.w) / denom;
        *(uint4*)(base + abyte) = pku(c0, c1);
        *(uint4*)(base + 4096 + bbyte0) = wh0;
        *(uint4*)(base + 4096 + bbyte1) = wh1;
    };
    STAGE(0);
    f32x4 acc[2] = {};
    int p = 0;
    for (int kt = 0; kt < DD; kt += 64) {
        __syncthreads();
        const bool more = (kt + 64 < DD);
        if (more) {
            FETCH((kt + 64) >> 6);
            wh0 = *(const uint4*)(WoTh + gB + kt + 64);
            wh1 = *(const uint4*)(WoTh + gB + kt + 72);
        }
        char* base = SM + p * 12288;
#pragma unroll
        for (int p2 = 0; p2 < 2; ++p2) {
            f16x8 ah = *(const f16x8*)(base + fA[p2]);
            f16x8 bh0 = *(const f16x8*)(base + 4096 + fB[0][p2]);
            f16x8 bh1 = *(const f16x8*)(base + 4096 + fB[1][p2]);
            acc[0] = __builtin_amdgcn_mfma_f32_16x16x32_f16(ah, bh0, acc[0], 0, 0, 0);
            acc[1] = __builtin_amdgcn_mfma_f32_16x16x32_f16(ah, bh1, acc[1], 0, 0, 0);
        }
        if (more) STAGE(p ^ 1);
        p ^= 1;
    }
#pragma unroll
    for (int j = 0; j < 2; ++j) {
        int cl = wn_ * 32 + j * 16 + la;
        float bb_ = bo[n0 + cl];
#pragma unroll
        for (int reg = 0; reg < 4; ++reg) {
            int rl = wm_ * 16 + gq * 4 + reg;
            out[(size_t)(m0 + rl) * DD + n0 + cl] = acc[j][reg] + bb_;
        }
    }
}

extern "C" void kernel_launch(void* const* d_in, const int* in_sizes, int n_in,
                              void* d_out, int out_size, void* d_ws, size_t ws_size,
                              hipStream_t stream) {
    const float* query = (const float*)d_in[0];
    const float* value = (const float*)d_in[2];
    const float* Wq = (const float*)d_in[4];
    const float* bq = (const float*)d_in[5];
    const float* Wv = (const float*)d_in[6];
    const float* bv = (const float*)d_in[7];
    const float* Wo = (const float*)d_in[8];
    const float* bo = (const float*)d_in[9];
    const float* rnd = (const float*)d_in[10];

    char* ws = (char*)d_ws;
    const size_t MB1 = 1u << 20;
    const size_t HK = 512u << 10;
    float*    Qf    = (float*)(ws);                       // [0,2MB)
    float*    Vf    = (float*)(ws + 2 * MB1);             // [2,4MB)
    float*    PV    = (float*)(ws + 4 * MB1);             // [4,8MB)
    ushort_t* WqTh  = (ushort_t*)(ws + 8 * MB1);
    ushort_t* WqTm  = (ushort_t*)(ws + 8 * MB1 + HK);
    ushort_t* WvTh  = (ushort_t*)(ws + 9 * MB1);
    ushort_t* WoTh  = (ushort_t*)(ws + 9 * MB1 + HK);
    float*    RNORM = (float*)(ws + 10 * MB1);
    char*     tail  = ws + 10 * MB1 + (64u << 10);
    int* HASH  = (int*)(tail);
    int* HIDX  = (int*)(tail + (64u << 10));
    int* OIDX  = (int*)(tail + (128u << 10));
    int* HSORT = (int*)(tail + (192u << 10));
    float2* ML = (float2*)(tail + (256u << 10));
    float* OUT = (float*)d_out;

    prep_w<<<768, 256, 0, stream>>>(Wq, Wv, Wo, WqTh, WqTm, WvTh, WoTh);
    gemm_hash<<<512, 256, 0, stream>>>(query, value, WqTh, WqTm, WvTh, bq, bv, rnd,
                                       Qf, Vf, HASH, RNORM);
    sort_kernel<<<16, 256, 0, stream>>>(HASH, HIDX, OIDX, HSORT);
    spv_kernel<<<dim3(32, 2, 8), 256, 0, stream>>>(Qf, RNORM, Vf, HIDX, OIDX, HSORT, PV, ML);
    out_combine<<<256, 256, 0, stream>>>(PV, ML, OIDX, WoTh, bo, OUT);
}